// Round 4
// baseline (12041.438 us; speedup 1.0000x reference)
//
#include <hip/hip_runtime.h>

namespace {

constexpr int Hn = 128, Wn = 128, HWn = 16384, HWFn = 8320;
constexpr float TWOPI_N = 0.049087385212340526f;   // 2*pi/128
constexpr float BN_SCALE = 0.99999500003749968f;   // 1/sqrt(1+1e-5)

// ---------- depthwise 3x3, pad 1 ----------
__global__ void k_dw3x3(const float* __restrict__ in, const float* __restrict__ w,
                        const float* __restrict__ bias, float* __restrict__ out, int C){
  int bc = blockIdx.x; int y = blockIdx.y; int x = threadIdx.x;
  int c = bc % C;
  const float* ip = in + (size_t)bc*HWn;
  const float* wp = w + c*9;
  float acc = bias ? bias[c] : 0.f;
  #pragma unroll
  for (int ky=0; ky<3; ky++){
    int yy = y + ky - 1; if (yy < 0 || yy >= Hn) continue;
    #pragma unroll
    for (int kx=0; kx<3; kx++){
      int xx = x + kx - 1; if (xx < 0 || xx >= Wn) continue;
      acc = fmaf(ip[yy*Wn+xx], wp[ky*3+kx], acc);
    }
  }
  out[(size_t)bc*HWn + y*Wn + x] = acc;
}

// ---------- pointwise 1x1; post: 0 none / 1 clip(-1,1) / 2 hardswish / 3 leaky(slope); optional BN ----------
__global__ void k_pw(const float* __restrict__ in, const float* __restrict__ wg,
                     const float* __restrict__ bias, const float* __restrict__ bng,
                     const float* __restrict__ bnb, float* __restrict__ out,
                     int Cin, int Cout, int npix, int inb, int outb, int post, float slope){
  int bo = blockIdx.x;
  int b = bo / Cout, o = bo - b*Cout;
  int p = blockIdx.y*256 + threadIdx.x;
  if (p >= npix) return;
  const float* ip = in + (size_t)b*inb + p;
  const float* wp = wg + (size_t)o*Cin;
  float acc = bias ? bias[o] : 0.f;
  for (int ci=0; ci<Cin; ci++) acc = fmaf(ip[(size_t)ci*npix], wp[ci], acc);
  if (bng) acc = acc*(bng[o]*BN_SCALE) + bnb[o];
  if (post == 1) acc = fminf(fmaxf(acc, -1.f), 1.f);
  else if (post == 2) acc = acc*fminf(fmaxf(acc+3.f, 0.f), 6.f)*(1.f/6.f);
  else if (post == 3) acc = (acc >= 0.f) ? acc : acc*slope;
  out[(size_t)b*outb + (size_t)o*npix + p] = acc;
}

// ---------- deformable depthwise 3x3 ----------
__global__ void k_deform(const float* __restrict__ x, const float* __restrict__ off,
                         const float* __restrict__ w, float* __restrict__ out, int C){
  int bc = blockIdx.x; int b = bc / C; int c = bc - b*C;
  int y = blockIdx.y; int x0 = threadIdx.x;
  const float* xp = x + (size_t)bc*HWn;
  const float* op = off + (size_t)b*18*HWn + y*Wn + x0;
  const float* wp = w + c*9;
  float acc = 0.f;
  #pragma unroll
  for (int k=0; k<9; k++){
    int ky = k/3 - 1, kx = k - (k/3)*3 - 1;
    float oy = op[(size_t)(2*k)*HWn];
    float ox = op[(size_t)(2*k+1)*HWn];
    float py = (float)y + (float)ky + oy;
    float px = (float)x0 + (float)kx + ox;
    float fy = floorf(py), fx = floorf(px);
    float wy = py - fy, wx = px - fx;
    int y0 = (int)fy, xx0 = (int)fx;
    float val = 0.f;
    #pragma unroll
    for (int dy=0; dy<2; dy++){
      int iy = y0 + dy; if (iy < 0 || iy >= Hn) continue;
      float wyv = dy ? wy : (1.f - wy);
      #pragma unroll
      for (int dx=0; dx<2; dx++){
        int ix = xx0 + dx; if (ix < 0 || ix >= Wn) continue;
        float wxv = dx ? wx : (1.f - wx);
        val = fmaf(xp[iy*Wn+ix], wyv*wxv, val);
      }
    }
    acc = fmaf(val, wp[k], acc);
  }
  out[(size_t)bc*HWn + y*Wn + x0] = acc;
}

// ---------- generic 3x3 conv, dilation d, pad d; OCPT outputs/thread; virtual concat [in | in2] at Csplit ----------
template<int OCPT>
__global__ void k_conv3x3(const float* __restrict__ in, const float* __restrict__ in2, int Csplit,
                          const float* __restrict__ wgt, const float* __restrict__ bias,
                          const float* __restrict__ res, float* __restrict__ out,
                          int Cin, int Cout, int dil, int leaky){
  int g = blockIdx.x; int ocg = Cout / OCPT;
  int b = g / ocg; int o0 = (g - b*ocg)*OCPT;
  int y = blockIdx.y, x = threadIdx.x;
  float acc[OCPT];
  #pragma unroll
  for (int j=0; j<OCPT; j++) acc[j] = bias ? bias[o0+j] : 0.f;
  for (int ci=0; ci<Cin; ci++){
    const float* iip;
    if (ci < Csplit) iip = in  + ((size_t)b*Csplit       + ci)          * HWn;
    else             iip = in2 + ((size_t)b*(Cin-Csplit) + (ci-Csplit)) * HWn;
    float v[9];
    #pragma unroll
    for (int ky=0; ky<3; ky++){
      int yy = y + (ky-1)*dil;
      bool yok = (yy >= 0 && yy < Hn);
      #pragma unroll
      for (int kx=0; kx<3; kx++){
        int xx = x + (kx-1)*dil;
        v[ky*3+kx] = (yok && xx >= 0 && xx < Wn) ? iip[yy*Wn+xx] : 0.f;
      }
    }
    #pragma unroll
    for (int j=0; j<OCPT; j++){
      const float* wp = wgt + ((size_t)(o0+j)*Cin + ci)*9;
      #pragma unroll
      for (int t=0; t<9; t++) acc[j] = fmaf(v[t], wp[t], acc[j]);
    }
  }
  #pragma unroll
  for (int j=0; j<OCPT; j++){
    float a = acc[j];
    if (leaky) a = (a >= 0.f) ? a : a*0.01f;
    size_t idx = ((size_t)b*Cout + o0 + j)*HWn + y*Wn + x;
    if (res) a += res[idx];
    out[idx] = a;
  }
}

// ---------- attention (per single batch) ----------
__global__ void k_scores(const float* __restrict__ q, const float* __restrict__ k,
                         float* __restrict__ s){
  // grid (128 h, 64 c), block 64 (d)
  int h = blockIdx.x; int c = blockIdx.y; int d = threadIdx.x;
  const float* qp = q + ((size_t)c*128 + h)*128;
  const float* kp = k + ((size_t)d*128 + h)*128;
  float acc = 0.f;
  for (int i=0; i<128; i++) acc = fmaf(qp[i], kp[i], acc);
  s[((size_t)h*64 + c)*64 + d] = acc * 0.35355339059327373f;  // 1/sqrt(8)
}
__global__ void k_softmax64(float* __restrict__ s, int nrows){
  int row = blockIdx.x*4 + (threadIdx.x >> 6);
  int lane = threadIdx.x & 63;
  if (row >= nrows) return;
  float v = s[(size_t)row*64 + lane];
  float m = v;
  for (int o=32; o>0; o>>=1) m = fmaxf(m, __shfl_xor(m, o));
  float e = expf(v - m);
  float sum = e;
  for (int o=32; o>0; o>>=1) sum += __shfl_xor(sum, o);
  s[(size_t)row*64 + lane] = e / sum;
}
__global__ void k_pv(const float* __restrict__ p, const float* __restrict__ v,
                     float* __restrict__ o){
  // grid (128 h, 64 c), block 128 (w)
  int h = blockIdx.x; int c = blockIdx.y; int w = threadIdx.x;
  const float* pp = p + ((size_t)h*64 + c)*64;
  const float* vp = v + (size_t)h*128 + w;
  float acc = 0.f;
  for (int d=0; d<64; d++) acc = fmaf(pp[d], vp[(size_t)d*HWn], acc);
  o[((size_t)c*128 + h)*128 + w] = acc;
}

// ---------- FFT via DFT (exact integer twiddle reduction) ----------
__global__ void k_rowfft(const float* __restrict__ x, float* __restrict__ re, float* __restrict__ im){
  __shared__ float xs[128], ct[128], st[128];
  int row = blockIdx.x; int t = threadIdx.x;
  xs[t] = x[(size_t)row*128 + t];
  ct[t] = cosf((float)t * TWOPI_N);
  st[t] = sinf((float)t * TWOPI_N);
  __syncthreads();
  if (t < 65){
    float ar = 0.f, ai = 0.f;
    for (int n=0; n<128; n++){
      int tw = (t*n) & 127;
      ar = fmaf(xs[n], ct[tw], ar);
      ai = fmaf(-xs[n], st[tw], ai);
    }
    re[(size_t)row*65 + t] = ar;
    im[(size_t)row*65 + t] = ai;
  }
}
__global__ void k_colfft(const float* __restrict__ re, const float* __restrict__ im,
                         float* __restrict__ cr, float* __restrict__ ci){
  // grid (imgs, 128 k), block 128 (w<65). layouts [img][8320]
  __shared__ float ct[128], st[128];
  int img = blockIdx.x; int kk = blockIdx.y; int w = threadIdx.x;
  ct[w] = cosf((float)w * TWOPI_N);
  st[w] = sinf((float)w * TWOPI_N);
  __syncthreads();
  if (w < 65){
    const float* rp = re + (size_t)img*HWFn + w;
    const float* ip = im + (size_t)img*HWFn + w;
    float ar = 0.f, ai = 0.f;
    for (int h=0; h<128; h++){
      int tw = (kk*h) & 127;
      float c = ct[tw], s = st[tw];
      float R = rp[h*65], I = ip[h*65];
      ar = fmaf(R, c, fmaf(I, s, ar));
      ai = fmaf(I, c, fmaf(-R, s, ai));
    }
    size_t o = (size_t)img*HWFn + kk*65 + w;
    cr[o] = ar; ci[o] = ai;
  }
}
// dst layout [nb][128 ch][8320], write ch 0..63. mode 0 mag / 1 pha. n = nb*64*8320
__global__ void k_magpha(const float* __restrict__ cr, const float* __restrict__ ci,
                         float* __restrict__ dst, int mode, int n){
  int i = blockIdx.x*256 + threadIdx.x;
  if (i >= n) return;
  int img = i / HWFn; int p = i - img*HWFn;
  int b = img >> 6, c = img & 63;
  float R = cr[i], I = ci[i];
  float v = mode ? atan2f(I, R) : sqrtf(R*R + I*I);
  dst[((size_t)b*128 + c)*HWFn + p] = v;
}
__global__ void k_recombine(const float* __restrict__ mo, const float* __restrict__ po,
                            float* __restrict__ R, float* __restrict__ I, int n){
  int i = blockIdx.x*256 + threadIdx.x;
  if (i < n){ float m = mo[i], p = po[i]; R[i] = m*cosf(p); I[i] = m*sinf(p); }
}
__global__ void k_hinv(const float* __restrict__ R, const float* __restrict__ I,
                       float* __restrict__ re2, float* __restrict__ im2){
  // grid (imgs, 128 h), block 128 (w<65)
  __shared__ float ct[128], st[128];
  int img = blockIdx.x; int hh = blockIdx.y; int w = threadIdx.x;
  ct[w] = cosf((float)w * TWOPI_N);
  st[w] = sinf((float)w * TWOPI_N);
  __syncthreads();
  if (w < 65){
    const float* rp = R + (size_t)img*HWFn + w;
    const float* ip = I + (size_t)img*HWFn + w;
    float ar = 0.f, ai = 0.f;
    for (int k2=0; k2<128; k2++){
      int tw = (k2*hh) & 127;
      float c = ct[tw], s = st[tw];
      float Rv = rp[k2*65], Iv = ip[k2*65];
      ar = fmaf(Rv, c, fmaf(-Iv, s, ar));
      ai = fmaf(Rv, s, fmaf(Iv, c, ai));
    }
    size_t o = ((size_t)img*128 + hh)*65 + w;
    re2[o] = ar * (1.f/128.f);
    im2[o] = ai * (1.f/128.f);
  }
}
__global__ void k_winv_add(const float* __restrict__ re2, const float* __restrict__ im2,
                           const float* __restrict__ hsrc, float* __restrict__ outp){
  // grid nrows, block 128 (n). pocketfft c2r: imag of bins 0 and 64 dropped.
  __shared__ float rs[65], is[65], ct[128], st[128];
  int row = blockIdx.x; int n = threadIdx.x;
  ct[n] = cosf((float)n * TWOPI_N);
  st[n] = sinf((float)n * TWOPI_N);
  if (n < 65){ rs[n] = re2[(size_t)row*65 + n]; is[n] = im2[(size_t)row*65 + n]; }
  __syncthreads();
  float acc = rs[0] + rs[64]*((n & 1) ? -1.f : 1.f);
  for (int k2=1; k2<64; k2++){
    int tw = (k2*n) & 127;
    acc = fmaf(2.f*rs[k2], ct[tw], fmaf(-2.f*is[k2], st[tw], acc));
  }
  acc *= (1.f/128.f);
  outp[(size_t)row*128 + n] = acc + hsrc[(size_t)row*128 + n];
}

} // namespace

extern "C" void kernel_launch(void* const* d_in, const int* in_sizes, int n_in,
                              void* d_out, int out_size, void* d_ws, size_t ws_size,
                              hipStream_t stream){
  // Inputs are FP32 (per the reference's jnp.float32 setup) — use directly.
  const float *xf   =(const float*)d_in[0],  *chodw=(const float*)d_in[1],
              *chopw=(const float*)d_in[2],  *chdcn=(const float*)d_in[3],
              *chpw =(const float*)d_in[4],  *ctodw=(const float*)d_in[5],
              *ctopw=(const float*)d_in[6],  *ctdcn=(const float*)d_in[7],
              *ctpw =(const float*)d_in[8],  *dbw  =(const float*)d_in[9],
              *dbb  =(const float*)d_in[10], *cadw =(const float*)d_in[11],
              *cadb =(const float*)d_in[12], *capw =(const float*)d_in[13],
              *capb =(const float*)d_in[14], *hhw  =(const float*)d_in[15],
              *hhb  =(const float*)d_in[16], *fd1w =(const float*)d_in[17],
              *fd2w =(const float*)d_in[18], *fd1g =(const float*)d_in[19],
              *fd1bt=(const float*)d_in[20], *fd2g =(const float*)d_in[21],
              *fd2bt=(const float*)d_in[22], *fcw  =(const float*)d_in[23],
              *cw   =(const float*)d_in[24], *cb   =(const float*)d_in[25];

  // --- workspace layout (floats), total 30,015,488 = 114.5 MiB ---
  constexpr size_t M = 1048576;            // one batch x 64ch x HW
  constexpr size_t CF2 = 2ull*64*HWFn;     // 1,064,960 (2-batch spectrum plane)
  float* ws = (float*)d_ws;
  float* h     = ws;                       // 12*M
  float* fftHL = ws + 12*M;                // 4*M
  float* cat6  = ws + 16*M;                // 12*6*HW = 1,179,648
  float* P     = cat6 + 1179648;           // pool: 11*M + 524,288 = 12,058,624
  // per-batch slots (phases 3-5)
  float* kb  = P;        float* vb  = P + M;   float* qb  = P + 2*M;
  float* qs  = P + 3*M;  float* aA  = P + 4*M; float* aB  = P + 5*M;
  float* aC  = P + 6*M;  float* hh1 = P + 7*M; float* sA  = P + 8*M;
  float* sB  = P + 9*M;  float* dil = P + 10*M;
  float* X   = P + 11*M;                   // 524,288: scores / offsets
  // phase-2 (2-batch chunk) aliases
  float* rowRe = P;            float* rowIm = P + CF2;
  float* colRe = P + 2*CF2;    float* colIm = P + 3*CF2;
  float* magBuf = P;           // 2 x 128 x 8320 = 2*CF2 (rowRe/rowIm dead after colfft)
  float* R4  = colRe;          float* I4  = colIm;
  float* re2 = P;              float* im2 = P + CF2;   // magBuf region (dead)
  // phase-1 aliases
  float* dwb3 = P; float* offb12 = P + 589824; float* yb3 = P + 4128768;

  float* out = (float*)d_out;
  float* out0 = out;                       // [12,3,128,128]     589,824
  float* out1 = out + 589824;              // mag [12,64,128,65] 6,389,760
  float* out2 = out + 589824 + 6389760;    // pha [12,64,128,65] 6,389,760

  auto PW = [&](const float* in, const float* wg, const float* bi, const float* g, const float* bt,
                float* o, int B, int Ci, int Co, int npix, int inb, int outb, int post, float slope){
    k_pw<<<dim3(B*Co, (npix+255)/256), 256, 0, stream>>>(in, wg, bi, g, bt, o, Ci, Co, npix, inb, outb, post, slope);
  };
  auto CONV3 = [&](const float* in, const float* in2, int split, const float* wg, const float* bi,
                   const float* res, float* o, int B, int Ci, int Co, int dl, int lk){
    k_conv3x3<4><<<dim3(B*(Co/4), Hn), 128, 0, stream>>>(in, in2, split, wg, bi, res, o, Ci, Co, dl, lk);
  };
  // single-batch dilated block: in preserved, result -> dil
  auto DIL1 = [&](const float* in, const float* wset, const float* bset){
    CONV3(in, nullptr, 64, wset,         bset,     nullptr, sA,  1, 64, 64, 1, 1);
    CONV3(sA, nullptr, 64, wset+36864,   bset+64,  nullptr, sB,  1, 64, 64, 2, 1);
    CONV3(sB, nullptr, 64, wset+2*36864, bset+128, nullptr, sA,  1, 64, 64, 3, 1);
    CONV3(sA, nullptr, 64, wset+3*36864, bset+192, nullptr, sB,  1, 64, 64, 2, 1);
    CONV3(sB, nullptr, 64, wset+4*36864, bset+256, in,      dil, 1, 64, 64, 1, 0);
  };
  // single-batch depth_conv (attention q/k/v), scratch qs
  auto DCONV1 = [&](const float* in, int idx, float* o){
    k_dw3x3<<<dim3(64, Hn), 128, 0, stream>>>(in, cadw + idx*576, cadb + idx*64, qs, 64);
    PW(qs, capw + (size_t)idx*4096, capb + idx*64, nullptr, nullptr, o, 1, 64, 64, HWn, 64*HWn, 64*HWn, 0, 0.f);
  };
  auto ATTN1 = [&](const float* qsrc, int qidx, float* o){
    DCONV1(qsrc, qidx, qb);
    k_scores<<<dim3(128, 64), 64, 0, stream>>>(qb, kb, X);
    k_softmax64<<<2048, 256, 0, stream>>>(X, 8192);
    k_pv<<<dim3(128, 64), 128, 0, stream>>>(X, vb, o);
  };
  // single-batch patch_embed(ct): scratch qs + X(offsets)
  auto PEMBED1 = [&](const float* in, float* outSlice){
    k_dw3x3<<<dim3(64, Hn), 128, 0, stream>>>(in, ctodw, nullptr, qs, 64);
    PW(qs, ctopw, nullptr, nullptr, nullptr, X, 1, 64, 18, HWn, 64*HWn, 18*HWn, 1, 0.f);
    k_deform<<<dim3(64, Hn), 128, 0, stream>>>(in, X, ctdcn, qs, 64);
    PW(qs, ctpw, nullptr, nullptr, nullptr, outSlice, 1, 64, 3, HWn, 64*HWn, 6*HWn, 2, 0.f);
  };

  // ===== Phase 1: patch_embed(ch) -> h (all 12 batches) =====
  k_dw3x3<<<dim3(36, Hn), 128, 0, stream>>>(xf, chodw, nullptr, dwb3, 3);
  PW(dwb3, chopw, nullptr, nullptr, nullptr, offb12, 12, 3, 18, HWn, 3*HWn, 18*HWn, 1, 0.f);
  k_deform<<<dim3(36, Hn), 128, 0, stream>>>(xf, offb12, chdcn, yb3, 3);
  PW(yb3, chpw, nullptr, nullptr, nullptr, h, 12, 3, 64, HWn, 3*HWn, 64*HWn, 2, 0.f);

  // ===== Phase 2: fft_block, 6 chunks of 2 batches =====
  for (int c=0; c<6; c++){
    const float* hsrc = h + (size_t)c*2*M;
    float* o1 = out1 + (size_t)c*CF2;
    float* o2 = out2 + (size_t)c*CF2;
    k_rowfft<<<16384, 128, 0, stream>>>(hsrc, rowRe, rowIm);
    k_colfft<<<dim3(128, 128), 128, 0, stream>>>(rowRe, rowIm, colRe, colIm);
    // mag branch: magBuf ch0-63 = mag, 64-95 = t, 96-127 = t2
    k_magpha<<<4160, 256, 0, stream>>>(colRe, colIm, magBuf, 0, (int)CF2);
    PW(magBuf, fd1w, nullptr, fd1g, fd1bt, magBuf + 64*HWFn, 2, 64, 32, HWFn, 128*HWFn, 128*HWFn, 3, 0.1f);
    PW(magBuf, fd2w, nullptr, fd2g, fd2bt, magBuf + 96*HWFn, 2, 96, 32, HWFn, 128*HWFn, 128*HWFn, 3, 0.1f);
    PW(magBuf, fcw,  nullptr, nullptr, nullptr, o1,          2, 128, 64, HWFn, 128*HWFn, 64*HWFn, 0, 0.f);
    // pha branch
    k_magpha<<<4160, 256, 0, stream>>>(colRe, colIm, magBuf, 1, (int)CF2);
    PW(magBuf, fd1w+2048, nullptr, fd1g+32, fd1bt+32, magBuf + 64*HWFn, 2, 64, 32, HWFn, 128*HWFn, 128*HWFn, 3, 0.1f);
    PW(magBuf, fd2w+3072, nullptr, fd2g+32, fd2bt+32, magBuf + 96*HWFn, 2, 96, 32, HWFn, 128*HWFn, 128*HWFn, 3, 0.1f);
    PW(magBuf, fcw+8192,  nullptr, nullptr, nullptr,  o2,    2, 128, 64, HWFn, 128*HWFn, 64*HWFn, 0, 0.f);
    if (c < 2){
      // irfft2 needed only for batches 0..3 (fft_HL); fft_LH/fft_HH are slices of h, not fft_out
      k_recombine<<<4160, 256, 0, stream>>>(o1, o2, R4, I4, (int)CF2);
      k_hinv<<<dim3(128, 128), 128, 0, stream>>>(R4, I4, re2, im2);
      k_winv_add<<<16384, 128, 0, stream>>>(re2, im2, hsrc, fftHL + (size_t)c*2*M);
    }
  }

  // ===== Phases 3-5 per batch g: attention, convHH, dilated, patch_embed -> cat6 =====
  for (int g=0; g<4; g++){
    const float* hHL = h + (size_t)g*M;          // x_HL = h[0:4]
    const float* hLH = h + (size_t)(4+g)*M;      // x_LH = h[4:8]
    const float* hHH = h + (size_t)(8+g)*M;      // x_HH = h[8:12]
    const float* fHL = fftHL + (size_t)g*M;
    // attention: f_HH_LH == x_HH_LH (fft_LH is a slice of h); ca1 k/v shared
    DCONV1(hHH, 1, kb);
    DCONV1(hHH, 2, vb);
    ATTN1(hLH, 0, aA);                           // attA = x_HH_LH
    DCONV1(hHH, 4, kb);
    DCONV1(hHH, 5, vb);
    ATTN1(hHL, 3, aB);                           // attB = x_HH_HL
    ATTN1(fHL, 3, aC);                           // attC = f_HH_HL
    // x_HH2 path
    CONV3(aA, aB, 64, hhw, hhb, nullptr, hh1, 1, 128, 64, 1, 0);
    DIL1(hh1, dbw + 2*184320, dbb + 2*320);
    PEMBED1(dil, cat6 + (size_t)((8+g)*6)*HWn);
    // f_HH2 path
    CONV3(aA, aC, 64, hhw, hhb, nullptr, hh1, 1, 128, 64, 1, 0);
    DIL1(hh1, dbw + 2*184320, dbb + 2*320);
    PEMBED1(dil, cat6 + (size_t)((8+g)*6+3)*HWn);
    // x_HL2 / x_LH2
    DIL1(hHL, dbw + 184320, dbb + 320);          // db[1]
    PEMBED1(dil, cat6 + (size_t)(g*6)*HWn);
    DIL1(hLH, dbw, dbb);                         // db[0]
    PEMBED1(dil, cat6 + (size_t)((4+g)*6)*HWn);
    // fft_HL / fft_LH passthroughs
    PEMBED1(fHL, cat6 + (size_t)(g*6+3)*HWn);
    PEMBED1(hLH, cat6 + (size_t)((4+g)*6+3)*HWn);
  }

  // ===== Final conv + residual -> out0 =====
  k_conv3x3<1><<<dim3(36, Hn), 128, 0, stream>>>(cat6, nullptr, 6, cw, cb, xf, out0, 6, 3, 1, 0);
}

// Round 5
// 7354.581 us; speedup vs baseline: 1.6373x; 1.6373x over previous
//
#include <hip/hip_runtime.h>

namespace {

constexpr int Hn = 128, Wn = 128, HWn = 16384, HWFn = 8320;
constexpr float TWOPI_N = 0.049087385212340526f;   // 2*pi/128
constexpr float BN_SCALE = 0.99999500003749968f;   // 1/sqrt(1+1e-5)

typedef __attribute__((ext_vector_type(8))) short short8;
typedef __attribute__((ext_vector_type(4))) float float4v;

__device__ __forceinline__ short f2bf(float v){
  unsigned u = __float_as_uint(v);
  u += 0x7FFF + ((u >> 16) & 1);          // RNE
  return (short)(u >> 16);
}

// ---------- weight pack to MFMA A-frag order (bf16) ----------
// packed[p][mt][lane][j], p = blk*18 + tap*2 + ks ; co=mt*16+(lane&15), ci=blk*64+ks*32+(lane>>4)*8+j
__global__ void k_pack(const float* __restrict__ w, unsigned short* __restrict__ o, int Cin, int n){
  int i = blockIdx.x*256 + threadIdx.x;
  if (i >= n) return;
  int j = i & 7, lane = (i>>3)&63, mt = (i>>9)&3, p = i>>11;
  int blk = p/18, r = p - blk*18, tap = r>>1, ks = r&1;
  int co = mt*16 + (lane & 15);
  int ci = blk*64 + ks*32 + ((lane>>4)<<3) + j;
  o[i] = (unsigned short)f2bf(w[((size_t)co*Cin + ci)*9 + tap]);
}

// ---------- MFMA 3x3 conv: Cout=64, one output row per WG ----------
// grid B*128, block 256. in/in2 fp32 [B][64][128][128]; nblk=2 => virtual concat.
constexpr int XST = 72;  // LDS x-stride (shorts); mult of 8 => 16B-aligned b128 reads
__global__ __launch_bounds__(256) void k_mconv(
    const float* __restrict__ in, const float* __restrict__ in2,
    const unsigned short* __restrict__ wpk, const float* __restrict__ bias,
    const float* __restrict__ res, float* __restrict__ out,
    int nblk, int dl, int leaky){
  __shared__ short lds[3*134*XST];
  int b = blockIdx.x >> 7, y = blockIdx.x & 127;
  int tid = threadIdx.x;
  int wv = tid >> 6, lane = tid & 63;
  int nq = lane >> 4, nr = lane & 15;
  float4v acc[4][2];
  #pragma unroll
  for (int mt=0; mt<4; mt++)
    #pragma unroll
    for (int nt=0; nt<2; nt++) acc[mt][nt] = (float4v){0.f,0.f,0.f,0.f};

  for (int blk=0; blk<nblk; blk++){
    const float* src = blk ? in2 : in;
    __syncthreads();
    for (int e = tid; e < 3*64*134; e += 256){
      int dy = e / (64*134); int r = e - dy*64*134;
      int ci = r / 134;      int x = r - ci*134;
      int yy = y + (dy-1)*dl;
      int xx = x - 3;
      float v = 0.f;
      if (yy >= 0 && yy < Hn && xx >= 0 && xx < Wn)
        v = src[(((size_t)b*64 + ci)*Hn + yy)*Wn + xx];
      lds[(dy*134 + x)*XST + ci] = f2bf(v);
    }
    __syncthreads();
    const unsigned short* wb = wpk + (size_t)blk*36864;
    for (int tap=0; tap<9; tap++){
      int dy = tap/3, dx = tap - (tap/3)*3;
      #pragma unroll
      for (int ks=0; ks<2; ks++){
        short8 a[4];
        #pragma unroll
        for (int mt=0; mt<4; mt++)
          a[mt] = *(const short8*)(wb + (((size_t)(tap*2+ks)*4+mt)<<9) + ((size_t)lane<<3));
        #pragma unroll
        for (int nt=0; nt<2; nt++){
          int x = wv*32 + nt*16 + nr + (dx-1)*dl + 3;
          short8 bf = *(const short8*)&lds[(dy*134 + x)*XST + ks*32 + nq*8];
          #pragma unroll
          for (int mt=0; mt<4; mt++)
            acc[mt][nt] = __builtin_amdgcn_mfma_f32_16x16x32_bf16(a[mt], bf, acc[mt][nt], 0, 0, 0);
        }
      }
    }
  }
  #pragma unroll
  for (int mt=0; mt<4; mt++)
  #pragma unroll
  for (int nt=0; nt<2; nt++){
    int x = wv*32 + nt*16 + nr;
    #pragma unroll
    for (int r2=0; r2<4; r2++){
      int co = mt*16 + nq*4 + r2;
      float a = acc[mt][nt][r2] + (bias ? bias[co] : 0.f);
      if (leaky) a = (a >= 0.f) ? a : 0.01f*a;
      size_t idx = (((size_t)b*64 + co)*Hn + y)*Wn + x;
      if (res) a += res[idx];
      out[idx] = a;
    }
  }
}

// ---------- depthwise 3x3, pad 1 ----------
__global__ void k_dw3x3(const float* __restrict__ in, const float* __restrict__ w,
                        const float* __restrict__ bias, float* __restrict__ out, int C){
  int bc = blockIdx.x; int y = blockIdx.y; int x = threadIdx.x;
  int c = bc % C;
  const float* ip = in + (size_t)bc*HWn;
  const float* wp = w + c*9;
  float acc = bias ? bias[c] : 0.f;
  #pragma unroll
  for (int ky=0; ky<3; ky++){
    int yy = y + ky - 1; if (yy < 0 || yy >= Hn) continue;
    #pragma unroll
    for (int kx=0; kx<3; kx++){
      int xx = x + kx - 1; if (xx < 0 || xx >= Wn) continue;
      acc = fmaf(ip[yy*Wn+xx], wp[ky*3+kx], acc);
    }
  }
  out[(size_t)bc*HWn + y*Wn + x] = acc;
}

// ---------- pointwise 1x1 ----------
__global__ void k_pw(const float* __restrict__ in, const float* __restrict__ wg,
                     const float* __restrict__ bias, const float* __restrict__ bng,
                     const float* __restrict__ bnb, float* __restrict__ out,
                     int Cin, int Cout, int npix, int inb, int outb, int post, float slope){
  int bo = blockIdx.x;
  int b = bo / Cout, o = bo - b*Cout;
  int p = blockIdx.y*256 + threadIdx.x;
  if (p >= npix) return;
  const float* ip = in + (size_t)b*inb + p;
  const float* wp = wg + (size_t)o*Cin;
  float acc = bias ? bias[o] : 0.f;
  for (int ci=0; ci<Cin; ci++) acc = fmaf(ip[(size_t)ci*npix], wp[ci], acc);
  if (bng) acc = acc*(bng[o]*BN_SCALE) + bnb[o];
  if (post == 1) acc = fminf(fmaxf(acc, -1.f), 1.f);
  else if (post == 2) acc = acc*fminf(fmaxf(acc+3.f, 0.f), 6.f)*(1.f/6.f);
  else if (post == 3) acc = (acc >= 0.f) ? acc : acc*slope;
  out[(size_t)b*outb + (size_t)o*npix + p] = acc;
}

// ---------- deformable depthwise 3x3 ----------
__global__ void k_deform(const float* __restrict__ x, const float* __restrict__ off,
                         const float* __restrict__ w, float* __restrict__ out, int C){
  int bc = blockIdx.x; int b = bc / C; int c = bc - b*C;
  int y = blockIdx.y; int x0 = threadIdx.x;
  const float* xp = x + (size_t)bc*HWn;
  const float* op = off + (size_t)b*18*HWn + y*Wn + x0;
  const float* wp = w + c*9;
  float acc = 0.f;
  #pragma unroll
  for (int k=0; k<9; k++){
    int ky = k/3 - 1, kx = k - (k/3)*3 - 1;
    float oy = op[(size_t)(2*k)*HWn];
    float ox = op[(size_t)(2*k+1)*HWn];
    float py = (float)y + (float)ky + oy;
    float px = (float)x0 + (float)kx + ox;
    float fy = floorf(py), fx = floorf(px);
    float wy = py - fy, wx = px - fx;
    int y0 = (int)fy, xx0 = (int)fx;
    float val = 0.f;
    #pragma unroll
    for (int dy=0; dy<2; dy++){
      int iy = y0 + dy; if (iy < 0 || iy >= Hn) continue;
      float wyv = dy ? wy : (1.f - wy);
      #pragma unroll
      for (int dx=0; dx<2; dx++){
        int ix = xx0 + dx; if (ix < 0 || ix >= Wn) continue;
        float wxv = dx ? wx : (1.f - wx);
        val = fmaf(xp[iy*Wn+ix], wyv*wxv, val);
      }
    }
    acc = fmaf(val, wp[k], acc);
  }
  out[(size_t)bc*HWn + y*Wn + x0] = acc;
}

// ---------- small direct conv (final 6->3) ----------
__global__ void k_conv3x3s(const float* __restrict__ in, const float* __restrict__ wgt,
                           const float* __restrict__ bias, const float* __restrict__ res,
                           float* __restrict__ out, int Cin, int Cout){
  int g = blockIdx.x;
  int b = g / Cout; int o0 = g - b*Cout;
  int y = blockIdx.y, x = threadIdx.x;
  float acc = bias ? bias[o0] : 0.f;
  for (int ci=0; ci<Cin; ci++){
    const float* iip = in + ((size_t)b*Cin + ci)*HWn;
    const float* wp = wgt + ((size_t)o0*Cin + ci)*9;
    #pragma unroll
    for (int ky=0; ky<3; ky++){
      int yy = y + ky - 1; if (yy < 0 || yy >= Hn) continue;
      #pragma unroll
      for (int kx=0; kx<3; kx++){
        int xx = x + kx - 1; if (xx < 0 || xx >= Wn) continue;
        acc = fmaf(iip[yy*Wn+xx], wp[ky*3+kx], acc);
      }
    }
  }
  size_t idx = ((size_t)b*Cout + o0)*HWn + y*Wn + x;
  if (res) acc += res[idx];
  out[idx] = acc;
}

// ---------- attention (batched) ----------
__global__ void k_scores(const float* __restrict__ q, const float* __restrict__ k,
                         float* __restrict__ s){
  // grid (B*128 bh, 64 c), block 64 (d)
  int bh = blockIdx.x; int b = bh >> 7; int h = bh & 127;
  int c = blockIdx.y; int d = threadIdx.x;
  const float* qp = q + (((size_t)b*64 + c)*128 + h)*128;
  const float* kp = k + (((size_t)b*64 + d)*128 + h)*128;
  float acc = 0.f;
  for (int i=0; i<128; i++) acc = fmaf(qp[i], kp[i], acc);
  s[((size_t)bh*64 + c)*64 + d] = acc * 0.35355339059327373f;  // 1/sqrt(8)
}
__global__ void k_softmax64(float* __restrict__ s, int nrows){
  int row = blockIdx.x*4 + (threadIdx.x >> 6);
  int lane = threadIdx.x & 63;
  if (row >= nrows) return;
  float v = s[(size_t)row*64 + lane];
  float m = v;
  for (int o=32; o>0; o>>=1) m = fmaxf(m, __shfl_xor(m, o));
  float e = expf(v - m);
  float sum = e;
  for (int o=32; o>0; o>>=1) sum += __shfl_xor(sum, o);
  s[(size_t)row*64 + lane] = e / sum;
}
__global__ void k_pv(const float* __restrict__ p, const float* __restrict__ v,
                     float* __restrict__ o){
  // grid (B*128 bh, 64 c), block 128 (w)
  int bh = blockIdx.x; int b = bh >> 7; int h = bh & 127;
  int c = blockIdx.y; int w = threadIdx.x;
  const float* pp = p + ((size_t)bh*64 + c)*64;
  const float* vp = v + ((size_t)b*64*128 + h)*128 + w;
  float acc = 0.f;
  for (int d=0; d<64; d++) acc = fmaf(pp[d], vp[(size_t)d*HWn], acc);
  o[(((size_t)b*64 + c)*128 + h)*128 + w] = acc;
}

// ---------- FFT via DFT ----------
__global__ void k_rowfft(const float* __restrict__ x, float* __restrict__ re, float* __restrict__ im){
  __shared__ float xs[128], ct[128], st[128];
  int row = blockIdx.x; int t = threadIdx.x;
  xs[t] = x[(size_t)row*128 + t];
  ct[t] = cosf((float)t * TWOPI_N);
  st[t] = sinf((float)t * TWOPI_N);
  __syncthreads();
  if (t < 65){
    float ar = 0.f, ai = 0.f;
    for (int n=0; n<128; n++){
      int tw = (t*n) & 127;
      ar = fmaf(xs[n], ct[tw], ar);
      ai = fmaf(-xs[n], st[tw], ai);
    }
    re[(size_t)row*65 + t] = ar;
    im[(size_t)row*65 + t] = ai;
  }
}
__global__ void k_colfft(const float* __restrict__ re, const float* __restrict__ im,
                         float* __restrict__ cr, float* __restrict__ ci){
  __shared__ float ct[128], st[128];
  int img = blockIdx.x; int kk = blockIdx.y; int w = threadIdx.x;
  ct[w] = cosf((float)w * TWOPI_N);
  st[w] = sinf((float)w * TWOPI_N);
  __syncthreads();
  if (w < 65){
    const float* rp = re + (size_t)img*HWFn + w;
    const float* ip = im + (size_t)img*HWFn + w;
    float ar = 0.f, ai = 0.f;
    for (int h=0; h<128; h++){
      int tw = (kk*h) & 127;
      float c = ct[tw], s = st[tw];
      float R = rp[h*65], I = ip[h*65];
      ar = fmaf(R, c, fmaf(I, s, ar));
      ai = fmaf(I, c, fmaf(-R, s, ai));
    }
    size_t o = (size_t)img*HWFn + kk*65 + w;
    cr[o] = ar; ci[o] = ai;
  }
}
__global__ void k_magpha(const float* __restrict__ cr, const float* __restrict__ ci,
                         float* __restrict__ dst, int mode, int n){
  int i = blockIdx.x*256 + threadIdx.x;
  if (i >= n) return;
  int img = i / HWFn; int p = i - img*HWFn;
  int b = img >> 6, c = img & 63;
  float R = cr[i], I = ci[i];
  float v = mode ? atan2f(I, R) : sqrtf(R*R + I*I);
  dst[((size_t)b*128 + c)*HWFn + p] = v;
}
__global__ void k_recombine(const float* __restrict__ mo, const float* __restrict__ po,
                            float* __restrict__ R, float* __restrict__ I, int n){
  int i = blockIdx.x*256 + threadIdx.x;
  if (i < n){ float m = mo[i], p = po[i]; R[i] = m*cosf(p); I[i] = m*sinf(p); }
}
__global__ void k_hinv(const float* __restrict__ R, const float* __restrict__ I,
                       float* __restrict__ re2, float* __restrict__ im2){
  __shared__ float ct[128], st[128];
  int img = blockIdx.x; int hh = blockIdx.y; int w = threadIdx.x;
  ct[w] = cosf((float)w * TWOPI_N);
  st[w] = sinf((float)w * TWOPI_N);
  __syncthreads();
  if (w < 65){
    const float* rp = R + (size_t)img*HWFn + w;
    const float* ip = I + (size_t)img*HWFn + w;
    float ar = 0.f, ai = 0.f;
    for (int k2=0; k2<128; k2++){
      int tw = (k2*hh) & 127;
      float c = ct[tw], s = st[tw];
      float Rv = rp[k2*65], Iv = ip[k2*65];
      ar = fmaf(Rv, c, fmaf(-Iv, s, ar));
      ai = fmaf(Rv, s, fmaf(Iv, c, ai));
    }
    size_t o = ((size_t)img*128 + hh)*65 + w;
    re2[o] = ar * (1.f/128.f);
    im2[o] = ai * (1.f/128.f);
  }
}
__global__ void k_winv_add(const float* __restrict__ re2, const float* __restrict__ im2,
                           const float* __restrict__ hsrc, float* __restrict__ outp){
  __shared__ float rs[65], is[65], ct[128], st[128];
  int row = blockIdx.x; int n = threadIdx.x;
  ct[n] = cosf((float)n * TWOPI_N);
  st[n] = sinf((float)n * TWOPI_N);
  if (n < 65){ rs[n] = re2[(size_t)row*65 + n]; is[n] = im2[(size_t)row*65 + n]; }
  __syncthreads();
  float acc = rs[0] + rs[64]*((n & 1) ? -1.f : 1.f);
  for (int k2=1; k2<64; k2++){
    int tw = (k2*n) & 127;
    acc = fmaf(2.f*rs[k2], ct[tw], fmaf(-2.f*is[k2], st[tw], acc));
  }
  acc *= (1.f/128.f);
  outp[(size_t)row*128 + n] = acc + hsrc[(size_t)row*128 + n];
}

} // namespace

extern "C" void kernel_launch(void* const* d_in, const int* in_sizes, int n_in,
                              void* d_out, int out_size, void* d_ws, size_t ws_size,
                              hipStream_t stream){
  const float *xf   =(const float*)d_in[0],  *chodw=(const float*)d_in[1],
              *chopw=(const float*)d_in[2],  *chdcn=(const float*)d_in[3],
              *chpw =(const float*)d_in[4],  *ctodw=(const float*)d_in[5],
              *ctopw=(const float*)d_in[6],  *ctdcn=(const float*)d_in[7],
              *ctpw =(const float*)d_in[8],  *dbw  =(const float*)d_in[9],
              *dbb  =(const float*)d_in[10], *cadw =(const float*)d_in[11],
              *cadb =(const float*)d_in[12], *capw =(const float*)d_in[13],
              *capb =(const float*)d_in[14], *hhw  =(const float*)d_in[15],
              *hhb  =(const float*)d_in[16], *fd1w =(const float*)d_in[17],
              *fd2w =(const float*)d_in[18], *fd1g =(const float*)d_in[19],
              *fd1bt=(const float*)d_in[20], *fd2g =(const float*)d_in[21],
              *fd2bt=(const float*)d_in[22], *fcw  =(const float*)d_in[23],
              *cw   =(const float*)d_in[24], *cb   =(const float*)d_in[25];

  constexpr size_t M = 1048576;            // one batch x 64ch x HW (floats)
  constexpr size_t CF2 = 2ull*64*HWFn;     // 1,064,960
  float* ws = (float*)d_ws;
  float* h     = ws;                       // 12*M
  float* fftHL = ws + 12*M;                // 4*M
  float* cat6  = ws + 16*M;                // 1,179,648
  unsigned short* wpkDB = (unsigned short*)(cat6 + 1179648);  // 15*36864 ush
  unsigned short* wpkHH = wpkDB + 552960;                     // 73728 ush
  float* P = cat6 + 1179648 + 313344;      // pool

  // NB=4 needs 266,018,816 bytes total; else per-batch (round-4-equivalent) path.
  const int NB = (ws_size >= 266018816ull) ? 4 : 1;
  const size_t S = (size_t)NB*M;
  float* kb  = P;        float* vb  = P + S;   float* qb  = P + 2*S;
  float* qs  = P + 3*S;  float* aA  = P + 4*S; float* aB  = P + 5*S;
  float* aC  = P + 6*S;  float* hh1 = P + 7*S; float* sA  = P + 8*S;
  float* sB  = P + 9*S;  float* dbuf= P + 10*S;
  float* X   = P + 11*S;                   // NB*524288: scores / offsets
  // phase-2 aliases (2-batch chunks)
  float* rowRe = P;            float* rowIm = P + CF2;
  float* colRe = P + 2*CF2;    float* colIm = P + 3*CF2;
  float* magBuf = P;
  float* R4  = colRe;          float* I4  = colIm;
  float* re2 = P;              float* im2 = P + CF2;
  // phase-1 aliases
  float* dwb3 = P; float* offb12 = P + 589824; float* yb3 = P + 4128768;

  float* out = (float*)d_out;
  float* out0 = out;
  float* out1 = out + 589824;
  float* out2 = out + 589824 + 6389760;

  auto PW = [&](const float* in, const float* wg, const float* bi, const float* g, const float* bt,
                float* o, int B, int Ci, int Co, int npix, int inb, int outb, int post, float slope){
    k_pw<<<dim3(B*Co, (npix+255)/256), 256, 0, stream>>>(in, wg, bi, g, bt, o, Ci, Co, npix, inb, outb, post, slope);
  };
  auto MCONV = [&](const float* in, const float* in2, const unsigned short* wp, const float* bi,
                   const float* res, float* o, int B, int nblk, int dl, int lk){
    k_mconv<<<B*128, 256, 0, stream>>>(in, in2, wp, bi, res, o, nblk, dl, lk);
  };
  // dilated block: in preserved, result -> dbuf (scratch sA/sB)
  auto DILm = [&](const float* in, int set, const float* bset, int B){
    const unsigned short* w5 = wpkDB + (size_t)set*5*36864;
    MCONV(in, nullptr, w5,          bset,      nullptr, sA,   B, 1, 1, 1);
    MCONV(sA, nullptr, w5+36864,    bset+64,   nullptr, sB,   B, 1, 2, 1);
    MCONV(sB, nullptr, w5+2*36864,  bset+128,  nullptr, sA,   B, 1, 3, 1);
    MCONV(sA, nullptr, w5+3*36864,  bset+192,  nullptr, sB,   B, 1, 2, 1);
    MCONV(sB, nullptr, w5+4*36864,  bset+256,  in,      dbuf, B, 1, 1, 0);
  };
  auto DCONVm = [&](const float* in, int idx, float* o, int B){
    k_dw3x3<<<dim3(B*64, Hn), 128, 0, stream>>>(in, cadw + idx*576, cadb + idx*64, qs, 64);
    PW(qs, capw + (size_t)idx*4096, capb + idx*64, nullptr, nullptr, o, B, 64, 64, HWn, 64*HWn, 64*HWn, 0, 0.f);
  };
  auto ATTNm = [&](const float* qsrc, int qidx, float* o, int B){
    DCONVm(qsrc, qidx, qb, B);
    k_scores<<<dim3(B*128, 64), 64, 0, stream>>>(qb, kb, X);
    k_softmax64<<<B*2048, 256, 0, stream>>>(X, B*8192);
    k_pv<<<dim3(B*128, 64), 128, 0, stream>>>(X, vb, o);
  };
  auto PEMBEDm = [&](const float* in, float* outSlice, int B){
    k_dw3x3<<<dim3(B*64, Hn), 128, 0, stream>>>(in, ctodw, nullptr, qs, 64);
    PW(qs, ctopw, nullptr, nullptr, nullptr, X, B, 64, 18, HWn, 64*HWn, 18*HWn, 1, 0.f);
    k_deform<<<dim3(B*64, Hn), 128, 0, stream>>>(in, X, ctdcn, qs, 64);
    PW(qs, ctpw, nullptr, nullptr, nullptr, outSlice, B, 64, 3, HWn, 64*HWn, 6*HWn, 2, 0.f);
  };

  // ===== Pack conv weights to bf16 A-frag order =====
  for (int c=0; c<15; c++)
    k_pack<<<144, 256, 0, stream>>>(dbw + (size_t)c*36864, wpkDB + (size_t)c*36864, 64, 36864);
  k_pack<<<288, 256, 0, stream>>>(hhw, wpkHH, 128, 73728);

  // ===== Phase 1: patch_embed(ch) -> h =====
  k_dw3x3<<<dim3(36, Hn), 128, 0, stream>>>(xf, chodw, nullptr, dwb3, 3);
  PW(dwb3, chopw, nullptr, nullptr, nullptr, offb12, 12, 3, 18, HWn, 3*HWn, 18*HWn, 1, 0.f);
  k_deform<<<dim3(36, Hn), 128, 0, stream>>>(xf, offb12, chdcn, yb3, 3);
  PW(yb3, chpw, nullptr, nullptr, nullptr, h, 12, 3, 64, HWn, 3*HWn, 64*HWn, 2, 0.f);

  // ===== Phase 2: fft_block, 6 chunks of 2 batches =====
  for (int c=0; c<6; c++){
    const float* hsrc = h + (size_t)c*2*M;
    float* o1 = out1 + (size_t)c*CF2;
    float* o2 = out2 + (size_t)c*CF2;
    k_rowfft<<<16384, 128, 0, stream>>>(hsrc, rowRe, rowIm);
    k_colfft<<<dim3(128, 128), 128, 0, stream>>>(rowRe, rowIm, colRe, colIm);
    k_magpha<<<4160, 256, 0, stream>>>(colRe, colIm, magBuf, 0, (int)CF2);
    PW(magBuf, fd1w, nullptr, fd1g, fd1bt, magBuf + 64*HWFn, 2, 64, 32, HWFn, 128*HWFn, 128*HWFn, 3, 0.1f);
    PW(magBuf, fd2w, nullptr, fd2g, fd2bt, magBuf + 96*HWFn, 2, 96, 32, HWFn, 128*HWFn, 128*HWFn, 3, 0.1f);
    PW(magBuf, fcw,  nullptr, nullptr, nullptr, o1,          2, 128, 64, HWFn, 128*HWFn, 64*HWFn, 0, 0.f);
    k_magpha<<<4160, 256, 0, stream>>>(colRe, colIm, magBuf, 1, (int)CF2);
    PW(magBuf, fd1w+2048, nullptr, fd1g+32, fd1bt+32, magBuf + 64*HWFn, 2, 64, 32, HWFn, 128*HWFn, 128*HWFn, 3, 0.1f);
    PW(magBuf, fd2w+3072, nullptr, fd2g+32, fd2bt+32, magBuf + 96*HWFn, 2, 96, 32, HWFn, 128*HWFn, 128*HWFn, 3, 0.1f);
    PW(magBuf, fcw+8192,  nullptr, nullptr, nullptr,  o2,    2, 128, 64, HWFn, 128*HWFn, 64*HWFn, 0, 0.f);
    if (c < 2){
      k_recombine<<<4160, 256, 0, stream>>>(o1, o2, R4, I4, (int)CF2);
      k_hinv<<<dim3(128, 128), 128, 0, stream>>>(R4, I4, re2, im2);
      k_winv_add<<<16384, 128, 0, stream>>>(re2, im2, hsrc, fftHL + (size_t)c*2*M);
    }
  }

  // ===== Phases 3-5 in groups of NB batches =====
  for (int g0=0; g0<4; g0+=NB){
    const float* hHL = h + (size_t)g0*M;
    const float* hLH = h + (size_t)(4+g0)*M;
    const float* hHH = h + (size_t)(8+g0)*M;
    const float* fHL = fftHL + (size_t)g0*M;
    DCONVm(hHH, 1, kb, NB);
    DCONVm(hHH, 2, vb, NB);
    ATTNm(hLH, 0, aA, NB);                       // x_HH_LH (== f_HH_LH)
    DCONVm(hHH, 4, kb, NB);
    DCONVm(hHH, 5, vb, NB);
    ATTNm(hHL, 3, aB, NB);                       // x_HH_HL
    ATTNm(fHL, 3, aC, NB);                       // f_HH_HL
    // x_HH2 path
    MCONV(aA, aB, wpkHH, hhb, nullptr, hh1, NB, 2, 1, 0);
    DILm(hh1, 2, dbb + 2*320, NB);
    PEMBEDm(dbuf, cat6 + (size_t)((8+g0)*6)*HWn, NB);
    // f_HH2 path
    MCONV(aA, aC, wpkHH, hhb, nullptr, hh1, NB, 2, 1, 0);
    DILm(hh1, 2, dbb + 2*320, NB);
    PEMBEDm(dbuf, cat6 + (size_t)((8+g0)*6+3)*HWn, NB);
    // x_HL2 / x_LH2
    DILm(hHL, 1, dbb + 320, NB);
    PEMBEDm(dbuf, cat6 + (size_t)(g0*6)*HWn, NB);
    DILm(hLH, 0, dbb, NB);
    PEMBEDm(dbuf, cat6 + (size_t)((4+g0)*6)*HWn, NB);
    // fft_HL / fft_LH passthroughs
    PEMBEDm(fHL, cat6 + (size_t)(g0*6+3)*HWn, NB);
    PEMBEDm(hLH, cat6 + (size_t)((4+g0)*6+3)*HWn, NB);
  }

  // ===== Final conv + residual -> out0 =====
  k_conv3x3s<<<dim3(36, Hn), 128, 0, stream>>>(cat6, cw, cb, xf, out0, 6, 3);
}

// Round 6
// 6294.854 us; speedup vs baseline: 1.9129x; 1.1683x over previous
//
#include <hip/hip_runtime.h>

namespace {

constexpr int Hn = 128, Wn = 128, HWn = 16384, HWFn = 8320;
constexpr float TWOPI_N = 0.049087385212340526f;   // 2*pi/128
constexpr float BN_SCALE = 0.99999500003749968f;   // 1/sqrt(1+1e-5)

typedef __attribute__((ext_vector_type(8))) short short8;
typedef __attribute__((ext_vector_type(4))) float float4v;

__device__ __forceinline__ short f2bf(float v){
  unsigned u = __float_as_uint(v);
  u += 0x7FFF + ((u >> 16) & 1);          // RNE
  return (short)(u >> 16);
}

// ---------- weight pack to MFMA A-frag order (bf16) ----------
__global__ void k_pack(const float* __restrict__ w, unsigned short* __restrict__ o, int Cin, int n){
  int i = blockIdx.x*256 + threadIdx.x;
  if (i >= n) return;
  int j = i & 7, lane = (i>>3)&63, mt = (i>>9)&3, p = i>>11;
  int blk = p/18, r = p - blk*18, tap = r>>1, ks = r&1;
  int co = mt*16 + (lane & 15);
  int ci = blk*64 + ks*32 + ((lane>>4)<<3) + j;
  o[i] = (unsigned short)f2bf(w[((size_t)co*Cin + ci)*9 + tap]);
}

// ---------- MFMA 3x3 conv: Cout=64, one output row per WG ----------
constexpr int XST = 72;
__global__ __launch_bounds__(256) void k_mconv(
    const float* __restrict__ in, const float* __restrict__ in2,
    const unsigned short* __restrict__ wpk, const float* __restrict__ bias,
    const float* __restrict__ res, float* __restrict__ out,
    int nblk, int dl, int leaky){
  __shared__ short lds[3*134*XST];
  int b = blockIdx.x >> 7, y = blockIdx.x & 127;
  int tid = threadIdx.x;
  int wv = tid >> 6, lane = tid & 63;
  int nq = lane >> 4, nr = lane & 15;
  float4v acc[4][2];
  #pragma unroll
  for (int mt=0; mt<4; mt++)
    #pragma unroll
    for (int nt=0; nt<2; nt++) acc[mt][nt] = (float4v){0.f,0.f,0.f,0.f};

  for (int blk=0; blk<nblk; blk++){
    const float* src = blk ? in2 : in;
    __syncthreads();
    for (int e = tid; e < 3*64*134; e += 256){
      int dy = e / (64*134); int r = e - dy*64*134;
      int ci = r / 134;      int x = r - ci*134;
      int yy = y + (dy-1)*dl;
      int xx = x - 3;
      float v = 0.f;
      if (yy >= 0 && yy < Hn && xx >= 0 && xx < Wn)
        v = src[(((size_t)b*64 + ci)*Hn + yy)*Wn + xx];
      lds[(dy*134 + x)*XST + ci] = f2bf(v);
    }
    __syncthreads();
    const unsigned short* wb = wpk + (size_t)blk*36864;
    for (int tap=0; tap<9; tap++){
      int dy = tap/3, dx = tap - (tap/3)*3;
      #pragma unroll
      for (int ks=0; ks<2; ks++){
        short8 a[4];
        #pragma unroll
        for (int mt=0; mt<4; mt++)
          a[mt] = *(const short8*)(wb + (((size_t)(tap*2+ks)*4+mt)<<9) + ((size_t)lane<<3));
        #pragma unroll
        for (int nt=0; nt<2; nt++){
          int x = wv*32 + nt*16 + nr + (dx-1)*dl + 3;
          short8 bf = *(const short8*)&lds[(dy*134 + x)*XST + ks*32 + nq*8];
          #pragma unroll
          for (int mt=0; mt<4; mt++)
            acc[mt][nt] = __builtin_amdgcn_mfma_f32_16x16x32_bf16(a[mt], bf, acc[mt][nt], 0, 0, 0);
        }
      }
    }
  }
  #pragma unroll
  for (int mt=0; mt<4; mt++)
  #pragma unroll
  for (int nt=0; nt<2; nt++){
    int x = wv*32 + nt*16 + nr;
    #pragma unroll
    for (int r2=0; r2<4; r2++){
      int co = mt*16 + nq*4 + r2;
      float a = acc[mt][nt][r2] + (bias ? bias[co] : 0.f);
      if (leaky) a = (a >= 0.f) ? a : 0.01f*a;
      size_t idx = (((size_t)b*64 + co)*Hn + y)*Wn + x;
      if (res) a += res[idx];
      out[idx] = a;
    }
  }
}

// ---------- depthwise 3x3, pad 1 ----------
__global__ void k_dw3x3(const float* __restrict__ in, const float* __restrict__ w,
                        const float* __restrict__ bias, float* __restrict__ out, int C){
  int bc = blockIdx.x; int y = blockIdx.y; int x = threadIdx.x;
  int c = bc % C;
  const float* ip = in + (size_t)bc*HWn;
  const float* wp = w + c*9;
  float acc = bias ? bias[c] : 0.f;
  #pragma unroll
  for (int ky=0; ky<3; ky++){
    int yy = y + ky - 1; if (yy < 0 || yy >= Hn) continue;
    #pragma unroll
    for (int kx=0; kx<3; kx++){
      int xx = x + kx - 1; if (xx < 0 || xx >= Wn) continue;
      acc = fmaf(ip[yy*Wn+xx], wp[ky*3+kx], acc);
    }
  }
  out[(size_t)bc*HWn + y*Wn + x] = acc;
}

// ---------- pointwise 1x1, register-tiled: thread owns pixel x CT outputs ----------
// grid (B*ntiles, ceil(npix/256)), block 256, dyn-LDS CT*Cin floats.
template<int CT>
__global__ void k_pwt(const float* __restrict__ in, const float* __restrict__ wg,
                      const float* __restrict__ bias, const float* __restrict__ bng,
                      const float* __restrict__ bnb, float* __restrict__ out,
                      int Cin, int Cout, int npix, int inb, int outb, int post, float slope){
  extern __shared__ float wsm[];
  int nt = (Cout + CT - 1)/CT;
  int b = blockIdx.x / nt, t = blockIdx.x - b*nt;
  int co0 = t*CT;
  // stage weight tile (broadcast-read later; wave-uniform addresses)
  for (int i = threadIdx.x; i < CT*Cin; i += 256){
    int co = i / Cin;
    wsm[i] = (co0 + co < Cout) ? wg[(size_t)(co0+co)*Cin + (i - co*Cin)] : 0.f;
  }
  __syncthreads();
  int p = blockIdx.y*256 + threadIdx.x;
  if (p >= npix) return;
  const float* ip = in + (size_t)b*inb + p;
  float acc[CT];
  #pragma unroll
  for (int j=0; j<CT; j++) acc[j] = 0.f;
  for (int ci=0; ci<Cin; ci++){
    float v = ip[(size_t)ci*npix];
    #pragma unroll
    for (int j=0; j<CT; j++) acc[j] = fmaf(v, wsm[j*Cin+ci], acc[j]);
  }
  #pragma unroll
  for (int j=0; j<CT; j++){
    int co = co0 + j;
    if (co < Cout){
      float a = acc[j] + (bias ? bias[co] : 0.f);
      if (bng) a = a*(bng[co]*BN_SCALE) + bnb[co];
      if (post == 1) a = fminf(fmaxf(a, -1.f), 1.f);
      else if (post == 2) a = a*fminf(fmaxf(a+3.f, 0.f), 6.f)*(1.f/6.f);
      else if (post == 3) a = (a >= 0.f) ? a : a*slope;
      out[(size_t)b*outb + (size_t)co*npix + p] = a;
    }
  }
}

// ---------- deformable depthwise 3x3 ----------
__global__ void k_deform(const float* __restrict__ x, const float* __restrict__ off,
                         const float* __restrict__ w, float* __restrict__ out, int C){
  int bc = blockIdx.x; int b = bc / C; int c = bc - b*C;
  int y = blockIdx.y; int x0 = threadIdx.x;
  const float* xp = x + (size_t)bc*HWn;
  const float* op = off + (size_t)b*18*HWn + y*Wn + x0;
  const float* wp = w + c*9;
  float acc = 0.f;
  #pragma unroll
  for (int k=0; k<9; k++){
    int ky = k/3 - 1, kx = k - (k/3)*3 - 1;
    float oy = op[(size_t)(2*k)*HWn];
    float ox = op[(size_t)(2*k+1)*HWn];
    float py = (float)y + (float)ky + oy;
    float px = (float)x0 + (float)kx + ox;
    float fy = floorf(py), fx = floorf(px);
    float wy = py - fy, wx = px - fx;
    int y0 = (int)fy, xx0 = (int)fx;
    float val = 0.f;
    #pragma unroll
    for (int dy=0; dy<2; dy++){
      int iy = y0 + dy; if (iy < 0 || iy >= Hn) continue;
      float wyv = dy ? wy : (1.f - wy);
      #pragma unroll
      for (int dx=0; dx<2; dx++){
        int ix = xx0 + dx; if (ix < 0 || ix >= Wn) continue;
        float wxv = dx ? wx : (1.f - wx);
        val = fmaf(xp[iy*Wn+ix], wyv*wxv, val);
      }
    }
    acc = fmaf(val, wp[k], acc);
  }
  out[(size_t)bc*HWn + y*Wn + x0] = acc;
}

// ---------- small direct conv (final 6->3) ----------
__global__ void k_conv3x3s(const float* __restrict__ in, const float* __restrict__ wgt,
                           const float* __restrict__ bias, const float* __restrict__ res,
                           float* __restrict__ out, int Cin, int Cout){
  int g = blockIdx.x;
  int b = g / Cout; int o0 = g - b*Cout;
  int y = blockIdx.y, x = threadIdx.x;
  float acc = bias ? bias[o0] : 0.f;
  for (int ci=0; ci<Cin; ci++){
    const float* iip = in + ((size_t)b*Cin + ci)*HWn;
    const float* wp = wgt + ((size_t)o0*Cin + ci)*9;
    #pragma unroll
    for (int ky=0; ky<3; ky++){
      int yy = y + ky - 1; if (yy < 0 || yy >= Hn) continue;
      #pragma unroll
      for (int kx=0; kx<3; kx++){
        int xx = x + kx - 1; if (xx < 0 || xx >= Wn) continue;
        acc = fmaf(iip[yy*Wn+xx], wp[ky*3+kx], acc);
      }
    }
  }
  size_t idx = ((size_t)b*Cout + o0)*HWn + y*Wn + x;
  if (res) acc += res[idx];
  out[idx] = acc;
}

// ---------- attention (batched) ----------
__global__ void k_scores(const float* __restrict__ q, const float* __restrict__ k,
                         float* __restrict__ s){
  int bh = blockIdx.x; int b = bh >> 7; int h = bh & 127;
  int c = blockIdx.y; int d = threadIdx.x;
  const float* qp = q + (((size_t)b*64 + c)*128 + h)*128;
  const float* kp = k + (((size_t)b*64 + d)*128 + h)*128;
  float acc = 0.f;
  for (int i=0; i<128; i++) acc = fmaf(qp[i], kp[i], acc);
  s[((size_t)bh*64 + c)*64 + d] = acc * 0.35355339059327373f;  // 1/sqrt(8)
}
__global__ void k_softmax64(float* __restrict__ s, int nrows){
  int row = blockIdx.x*4 + (threadIdx.x >> 6);
  int lane = threadIdx.x & 63;
  if (row >= nrows) return;
  float v = s[(size_t)row*64 + lane];
  float m = v;
  for (int o=32; o>0; o>>=1) m = fmaxf(m, __shfl_xor(m, o));
  float e = expf(v - m);
  float sum = e;
  for (int o=32; o>0; o>>=1) sum += __shfl_xor(sum, o);
  s[(size_t)row*64 + lane] = e / sum;
}
__global__ void k_pv(const float* __restrict__ p, const float* __restrict__ v,
                     float* __restrict__ o){
  int bh = blockIdx.x; int b = bh >> 7; int h = bh & 127;
  int c = blockIdx.y; int w = threadIdx.x;
  const float* pp = p + ((size_t)bh*64 + c)*64;
  const float* vp = v + ((size_t)b*64*128 + h)*128 + w;
  float acc = 0.f;
  for (int d=0; d<64; d++) acc = fmaf(pp[d], vp[(size_t)d*HWn], acc);
  o[(((size_t)b*64 + c)*128 + h)*128 + w] = acc;
}

// ---------- FFT via DFT ----------
__global__ void k_rowfft(const float* __restrict__ x, float* __restrict__ re, float* __restrict__ im){
  __shared__ float xs[128], ct[128], st[128];
  int row = blockIdx.x; int t = threadIdx.x;
  xs[t] = x[(size_t)row*128 + t];
  ct[t] = cosf((float)t * TWOPI_N);
  st[t] = sinf((float)t * TWOPI_N);
  __syncthreads();
  if (t < 65){
    float ar = 0.f, ai = 0.f;
    for (int n=0; n<128; n++){
      int tw = (t*n) & 127;
      ar = fmaf(xs[n], ct[tw], ar);
      ai = fmaf(-xs[n], st[tw], ai);
    }
    re[(size_t)row*65 + t] = ar;
    im[(size_t)row*65 + t] = ai;
  }
}
__global__ void k_colfft(const float* __restrict__ re, const float* __restrict__ im,
                         float* __restrict__ cr, float* __restrict__ ci){
  __shared__ float ct[128], st[128];
  int img = blockIdx.x; int kk = blockIdx.y; int w = threadIdx.x;
  ct[w] = cosf((float)w * TWOPI_N);
  st[w] = sinf((float)w * TWOPI_N);
  __syncthreads();
  if (w < 65){
    const float* rp = re + (size_t)img*HWFn + w;
    const float* ip = im + (size_t)img*HWFn + w;
    float ar = 0.f, ai = 0.f;
    for (int h=0; h<128; h++){
      int tw = (kk*h) & 127;
      float c = ct[tw], s = st[tw];
      float R = rp[h*65], I = ip[h*65];
      ar = fmaf(R, c, fmaf(I, s, ar));
      ai = fmaf(I, c, fmaf(-R, s, ai));
    }
    size_t o = (size_t)img*HWFn + kk*65 + w;
    cr[o] = ar; ci[o] = ai;
  }
}
__global__ void k_magpha(const float* __restrict__ cr, const float* __restrict__ ci,
                         float* __restrict__ dst, int mode, int n){
  int i = blockIdx.x*256 + threadIdx.x;
  if (i >= n) return;
  int img = i / HWFn; int p = i - img*HWFn;
  int b = img >> 6, c = img & 63;
  float R = cr[i], I = ci[i];
  float v = mode ? atan2f(I, R) : sqrtf(R*R + I*I);
  dst[((size_t)b*128 + c)*HWFn + p] = v;
}
__global__ void k_recombine(const float* __restrict__ mo, const float* __restrict__ po,
                            float* __restrict__ R, float* __restrict__ I, int n){
  int i = blockIdx.x*256 + threadIdx.x;
  if (i < n){ float m = mo[i], p = po[i]; R[i] = m*cosf(p); I[i] = m*sinf(p); }
}
__global__ void k_hinv(const float* __restrict__ R, const float* __restrict__ I,
                       float* __restrict__ re2, float* __restrict__ im2){
  __shared__ float ct[128], st[128];
  int img = blockIdx.x; int hh = blockIdx.y; int w = threadIdx.x;
  ct[w] = cosf((float)w * TWOPI_N);
  st[w] = sinf((float)w * TWOPI_N);
  __syncthreads();
  if (w < 65){
    const float* rp = R + (size_t)img*HWFn + w;
    const float* ip = I + (size_t)img*HWFn + w;
    float ar = 0.f, ai = 0.f;
    for (int k2=0; k2<128; k2++){
      int tw = (k2*hh) & 127;
      float c = ct[tw], s = st[tw];
      float Rv = rp[k2*65], Iv = ip[k2*65];
      ar = fmaf(Rv, c, fmaf(-Iv, s, ar));
      ai = fmaf(Rv, s, fmaf(Iv, c, ai));
    }
    size_t o = ((size_t)img*128 + hh)*65 + w;
    re2[o] = ar * (1.f/128.f);
    im2[o] = ai * (1.f/128.f);
  }
}
__global__ void k_winv_add(const float* __restrict__ re2, const float* __restrict__ im2,
                           const float* __restrict__ hsrc, float* __restrict__ outp){
  __shared__ float rs[65], is[65], ct[128], st[128];
  int row = blockIdx.x; int n = threadIdx.x;
  ct[n] = cosf((float)n * TWOPI_N);
  st[n] = sinf((float)n * TWOPI_N);
  if (n < 65){ rs[n] = re2[(size_t)row*65 + n]; is[n] = im2[(size_t)row*65 + n]; }
  __syncthreads();
  float acc = rs[0] + rs[64]*((n & 1) ? -1.f : 1.f);
  for (int k2=1; k2<64; k2++){
    int tw = (k2*n) & 127;
    acc = fmaf(2.f*rs[k2], ct[tw], fmaf(-2.f*is[k2], st[tw], acc));
  }
  acc *= (1.f/128.f);
  outp[(size_t)row*128 + n] = acc + hsrc[(size_t)row*128 + n];
}

} // namespace

extern "C" void kernel_launch(void* const* d_in, const int* in_sizes, int n_in,
                              void* d_out, int out_size, void* d_ws, size_t ws_size,
                              hipStream_t stream){
  const float *xf   =(const float*)d_in[0],  *chodw=(const float*)d_in[1],
              *chopw=(const float*)d_in[2],  *chdcn=(const float*)d_in[3],
              *chpw =(const float*)d_in[4],  *ctodw=(const float*)d_in[5],
              *ctopw=(const float*)d_in[6],  *ctdcn=(const float*)d_in[7],
              *ctpw =(const float*)d_in[8],  *dbw  =(const float*)d_in[9],
              *dbb  =(const float*)d_in[10], *cadw =(const float*)d_in[11],
              *cadb =(const float*)d_in[12], *capw =(const float*)d_in[13],
              *capb =(const float*)d_in[14], *hhw  =(const float*)d_in[15],
              *hhb  =(const float*)d_in[16], *fd1w =(const float*)d_in[17],
              *fd2w =(const float*)d_in[18], *fd1g =(const float*)d_in[19],
              *fd1bt=(const float*)d_in[20], *fd2g =(const float*)d_in[21],
              *fd2bt=(const float*)d_in[22], *fcw  =(const float*)d_in[23],
              *cw   =(const float*)d_in[24], *cb   =(const float*)d_in[25];

  constexpr size_t M = 1048576;            // one batch x 64ch x HW (floats)
  constexpr size_t CF2 = 2ull*64*HWFn;     // 1,064,960
  float* ws = (float*)d_ws;
  float* h     = ws;                       // 12*M
  float* fftHL = ws + 12*M;                // 4*M
  float* cat6  = ws + 16*M;                // 1,179,648
  unsigned short* wpkDB = (unsigned short*)(cat6 + 1179648);  // 15*36864 ush
  unsigned short* wpkHH = wpkDB + 552960;                     // 73728 ush
  float* P = cat6 + 1179648 + 313344;      // pool

  const int NB = (ws_size >= 266018816ull) ? 4 : 1;
  const size_t S = (size_t)NB*M;
  float* kb  = P;        float* vb  = P + S;   float* qb  = P + 2*S;
  float* qs  = P + 3*S;  float* aA  = P + 4*S; float* aB  = P + 5*S;
  float* aC  = P + 6*S;  float* hh1 = P + 7*S; float* sA  = P + 8*S;
  float* sB  = P + 9*S;  float* dbuf= P + 10*S;
  float* X   = P + 11*S;
  // phase-2 aliases (2-batch chunks)
  float* rowRe = P;            float* rowIm = P + CF2;
  float* colRe = P + 2*CF2;    float* colIm = P + 3*CF2;
  float* magBuf = P;
  float* R4  = colRe;          float* I4  = colIm;
  float* re2 = P;              float* im2 = P + CF2;
  // phase-1 aliases
  float* dwb3 = P; float* offb12 = P + 589824; float* yb3 = P + 4128768;

  float* out = (float*)d_out;
  float* out0 = out;
  float* out1 = out + 589824;
  float* out2 = out + 589824 + 6389760;

  // PW dispatch: pick co-tile template by Cout
  auto PW = [&](const float* in, const float* wg, const float* bi, const float* g, const float* bt,
                float* o, int B, int Ci, int Co, int npix, int inb, int outb, int post, float slope){
    int py = (npix + 255)/256;
    if (Co > 32){            // 64 -> 2 tiles of 32
      k_pwt<32><<<dim3(B*2, py), 256, 32*Ci*4, stream>>>(in, wg, bi, g, bt, o, Ci, Co, npix, inb, outb, post, slope);
    } else if (Co > 18){     // 32
      k_pwt<32><<<dim3(B, py), 256, 32*Ci*4, stream>>>(in, wg, bi, g, bt, o, Ci, Co, npix, inb, outb, post, slope);
    } else if (Co > 3){      // 18
      k_pwt<18><<<dim3(B, py), 256, 18*Ci*4, stream>>>(in, wg, bi, g, bt, o, Ci, Co, npix, inb, outb, post, slope);
    } else {                 // 3
      k_pwt<3><<<dim3(B, py), 256, 3*Ci*4, stream>>>(in, wg, bi, g, bt, o, Ci, Co, npix, inb, outb, post, slope);
    }
  };
  auto MCONV = [&](const float* in, const float* in2, const unsigned short* wp, const float* bi,
                   const float* res, float* o, int B, int nblk, int dl, int lk){
    k_mconv<<<B*128, 256, 0, stream>>>(in, in2, wp, bi, res, o, nblk, dl, lk);
  };
  auto DILm = [&](const float* in, int set, const float* bset, int B){
    const unsigned short* w5 = wpkDB + (size_t)set*5*36864;
    MCONV(in, nullptr, w5,          bset,      nullptr, sA,   B, 1, 1, 1);
    MCONV(sA, nullptr, w5+36864,    bset+64,   nullptr, sB,   B, 1, 2, 1);
    MCONV(sB, nullptr, w5+2*36864,  bset+128,  nullptr, sA,   B, 1, 3, 1);
    MCONV(sA, nullptr, w5+3*36864,  bset+192,  nullptr, sB,   B, 1, 2, 1);
    MCONV(sB, nullptr, w5+4*36864,  bset+256,  in,      dbuf, B, 1, 1, 0);
  };
  auto DCONVm = [&](const float* in, int idx, float* o, int B){
    k_dw3x3<<<dim3(B*64, Hn), 128, 0, stream>>>(in, cadw + idx*576, cadb + idx*64, qs, 64);
    PW(qs, capw + (size_t)idx*4096, capb + idx*64, nullptr, nullptr, o, B, 64, 64, HWn, 64*HWn, 64*HWn, 0, 0.f);
  };
  auto ATTNm = [&](const float* qsrc, int qidx, float* o, int B){
    DCONVm(qsrc, qidx, qb, B);
    k_scores<<<dim3(B*128, 64), 64, 0, stream>>>(qb, kb, X);
    k_softmax64<<<B*2048, 256, 0, stream>>>(X, B*8192);
    k_pv<<<dim3(B*128, 64), 128, 0, stream>>>(X, vb, o);
  };
  auto PEMBEDm = [&](const float* in, float* outSlice, int B){
    k_dw3x3<<<dim3(B*64, Hn), 128, 0, stream>>>(in, ctodw, nullptr, qs, 64);
    PW(qs, ctopw, nullptr, nullptr, nullptr, X, B, 64, 18, HWn, 64*HWn, 18*HWn, 1, 0.f);
    k_deform<<<dim3(B*64, Hn), 128, 0, stream>>>(in, X, ctdcn, qs, 64);
    PW(qs, ctpw, nullptr, nullptr, nullptr, outSlice, B, 64, 3, HWn, 64*HWn, 6*HWn, 2, 0.f);
  };

  // ===== Pack conv weights to bf16 A-frag order =====
  for (int c=0; c<15; c++)
    k_pack<<<144, 256, 0, stream>>>(dbw + (size_t)c*36864, wpkDB + (size_t)c*36864, 64, 36864);
  k_pack<<<288, 256, 0, stream>>>(hhw, wpkHH, 128, 73728);

  // ===== Phase 1: patch_embed(ch) -> h =====
  k_dw3x3<<<dim3(36, Hn), 128, 0, stream>>>(xf, chodw, nullptr, dwb3, 3);
  PW(dwb3, chopw, nullptr, nullptr, nullptr, offb12, 12, 3, 18, HWn, 3*HWn, 18*HWn, 1, 0.f);
  k_deform<<<dim3(36, Hn), 128, 0, stream>>>(xf, offb12, chdcn, yb3, 3);
  PW(yb3, chpw, nullptr, nullptr, nullptr, h, 12, 3, 64, HWn, 3*HWn, 64*HWn, 2, 0.f);

  // ===== Phase 2: fft_block, 6 chunks of 2 batches =====
  for (int c=0; c<6; c++){
    const float* hsrc = h + (size_t)c*2*M;
    float* o1 = out1 + (size_t)c*CF2;
    float* o2 = out2 + (size_t)c*CF2;
    k_rowfft<<<16384, 128, 0, stream>>>(hsrc, rowRe, rowIm);
    k_colfft<<<dim3(128, 128), 128, 0, stream>>>(rowRe, rowIm, colRe, colIm);
    k_magpha<<<4160, 256, 0, stream>>>(colRe, colIm, magBuf, 0, (int)CF2);
    PW(magBuf, fd1w, nullptr, fd1g, fd1bt, magBuf + 64*HWFn, 2, 64, 32, HWFn, 128*HWFn, 128*HWFn, 3, 0.1f);
    PW(magBuf, fd2w, nullptr, fd2g, fd2bt, magBuf + 96*HWFn, 2, 96, 32, HWFn, 128*HWFn, 128*HWFn, 3, 0.1f);
    PW(magBuf, fcw,  nullptr, nullptr, nullptr, o1,          2, 128, 64, HWFn, 128*HWFn, 64*HWFn, 0, 0.f);
    k_magpha<<<4160, 256, 0, stream>>>(colRe, colIm, magBuf, 1, (int)CF2);
    PW(magBuf, fd1w+2048, nullptr, fd1g+32, fd1bt+32, magBuf + 64*HWFn, 2, 64, 32, HWFn, 128*HWFn, 128*HWFn, 3, 0.1f);
    PW(magBuf, fd2w+3072, nullptr, fd2g+32, fd2bt+32, magBuf + 96*HWFn, 2, 96, 32, HWFn, 128*HWFn, 128*HWFn, 3, 0.1f);
    PW(magBuf, fcw+8192,  nullptr, nullptr, nullptr,  o2,    2, 128, 64, HWFn, 128*HWFn, 64*HWFn, 0, 0.f);
    if (c < 2){
      k_recombine<<<4160, 256, 0, stream>>>(o1, o2, R4, I4, (int)CF2);
      k_hinv<<<dim3(128, 128), 128, 0, stream>>>(R4, I4, re2, im2);
      k_winv_add<<<16384, 128, 0, stream>>>(re2, im2, hsrc, fftHL + (size_t)c*2*M);
    }
  }

  // ===== Phases 3-5 in groups of NB batches =====
  for (int g0=0; g0<4; g0+=NB){
    const float* hHL = h + (size_t)g0*M;
    const float* hLH = h + (size_t)(4+g0)*M;
    const float* hHH = h + (size_t)(8+g0)*M;
    const float* fHL = fftHL + (size_t)g0*M;
    DCONVm(hHH, 1, kb, NB);
    DCONVm(hHH, 2, vb, NB);
    ATTNm(hLH, 0, aA, NB);                       // x_HH_LH (== f_HH_LH)
    DCONVm(hHH, 4, kb, NB);
    DCONVm(hHH, 5, vb, NB);
    ATTNm(hHL, 3, aB, NB);                       // x_HH_HL
    ATTNm(fHL, 3, aC, NB);                       // f_HH_HL
    // x_HH2 path
    MCONV(aA, aB, wpkHH, hhb, nullptr, hh1, NB, 2, 1, 0);
    DILm(hh1, 2, dbb + 2*320, NB);
    PEMBEDm(dbuf, cat6 + (size_t)((8+g0)*6)*HWn, NB);
    // f_HH2 path
    MCONV(aA, aC, wpkHH, hhb, nullptr, hh1, NB, 2, 1, 0);
    DILm(hh1, 2, dbb + 2*320, NB);
    PEMBEDm(dbuf, cat6 + (size_t)((8+g0)*6+3)*HWn, NB);
    // x_HL2 / x_LH2
    DILm(hHL, 1, dbb + 320, NB);
    PEMBEDm(dbuf, cat6 + (size_t)(g0*6)*HWn, NB);
    DILm(hLH, 0, dbb, NB);
    PEMBEDm(dbuf, cat6 + (size_t)((4+g0)*6)*HWn, NB);
    // fft_HL / fft_LH passthroughs
    PEMBEDm(fHL, cat6 + (size_t)(g0*6+3)*HWn, NB);
    PEMBEDm(hLH, cat6 + (size_t)((4+g0)*6+3)*HWn, NB);
  }

  // ===== Final conv + residual -> out0 =====
  k_conv3x3s<<<dim3(36, Hn), 128, 0, stream>>>(cat6, cw, cb, xf, out0, 6, 3);
}

// Round 7
// 4571.438 us; speedup vs baseline: 2.6341x; 1.3770x over previous
//
#include <hip/hip_runtime.h>

namespace {

constexpr int Hn = 128, Wn = 128, HWn = 16384, HWFn = 8320;
constexpr float TWOPI_N = 0.049087385212340526f;   // 2*pi/128
constexpr float BN_SCALE = 0.99999500003749968f;   // 1/sqrt(1+1e-5)

typedef __attribute__((ext_vector_type(8))) short short8;
typedef __attribute__((ext_vector_type(4))) float float4v;

__device__ __forceinline__ short f2bf(float v){
  unsigned u = __float_as_uint(v);
  u += 0x7FFF + ((u >> 16) & 1);          // RNE
  return (short)(u >> 16);
}

// ---------- weight pack to MFMA A-frag order (bf16) ----------
__global__ void k_pack(const float* __restrict__ w, unsigned short* __restrict__ o, int Cin, int n){
  int i = blockIdx.x*256 + threadIdx.x;
  if (i >= n) return;
  int j = i & 7, lane = (i>>3)&63, mt = (i>>9)&3, p = i>>11;
  int blk = p/18, r = p - blk*18, tap = r>>1, ks = r&1;
  int co = mt*16 + (lane & 15);
  int ci = blk*64 + ks*32 + ((lane>>4)<<3) + j;
  o[i] = (unsigned short)f2bf(w[((size_t)co*Cin + ci)*9 + tap]);
}

// ---------- MFMA 3x3 conv: Cout=64, one output row per WG ----------
constexpr int XST = 72;
__global__ __launch_bounds__(256) void k_mconv(
    const float* __restrict__ in, const float* __restrict__ in2,
    const unsigned short* __restrict__ wpk, const float* __restrict__ bias,
    const float* __restrict__ res, float* __restrict__ out,
    int nblk, int dl, int leaky){
  __shared__ short lds[3*134*XST];
  int b = blockIdx.x >> 7, y = blockIdx.x & 127;
  int tid = threadIdx.x;
  int wv = tid >> 6, lane = tid & 63;
  int nq = lane >> 4, nr = lane & 15;
  float4v acc[4][2];
  #pragma unroll
  for (int mt=0; mt<4; mt++)
    #pragma unroll
    for (int nt=0; nt<2; nt++) acc[mt][nt] = (float4v){0.f,0.f,0.f,0.f};

  for (int blk=0; blk<nblk; blk++){
    const float* src = blk ? in2 : in;
    __syncthreads();
    for (int e = tid; e < 3*64*134; e += 256){
      int dy = e / (64*134); int r = e - dy*64*134;
      int ci = r / 134;      int x = r - ci*134;
      int yy = y + (dy-1)*dl;
      int xx = x - 3;
      float v = 0.f;
      if (yy >= 0 && yy < Hn && xx >= 0 && xx < Wn)
        v = src[(((size_t)b*64 + ci)*Hn + yy)*Wn + xx];
      lds[(dy*134 + x)*XST + ci] = f2bf(v);
    }
    __syncthreads();
    const unsigned short* wb = wpk + (size_t)blk*36864;
    for (int tap=0; tap<9; tap++){
      int dy = tap/3, dx = tap - (tap/3)*3;
      #pragma unroll
      for (int ks=0; ks<2; ks++){
        short8 a[4];
        #pragma unroll
        for (int mt=0; mt<4; mt++)
          a[mt] = *(const short8*)(wb + (((size_t)(tap*2+ks)*4+mt)<<9) + ((size_t)lane<<3));
        #pragma unroll
        for (int nt=0; nt<2; nt++){
          int x = wv*32 + nt*16 + nr + (dx-1)*dl + 3;
          short8 bf = *(const short8*)&lds[(dy*134 + x)*XST + ks*32 + nq*8];
          #pragma unroll
          for (int mt=0; mt<4; mt++)
            acc[mt][nt] = __builtin_amdgcn_mfma_f32_16x16x32_bf16(a[mt], bf, acc[mt][nt], 0, 0, 0);
        }
      }
    }
  }
  #pragma unroll
  for (int mt=0; mt<4; mt++)
  #pragma unroll
  for (int nt=0; nt<2; nt++){
    int x = wv*32 + nt*16 + nr;
    #pragma unroll
    for (int r2=0; r2<4; r2++){
      int co = mt*16 + nq*4 + r2;
      float a = acc[mt][nt][r2] + (bias ? bias[co] : 0.f);
      if (leaky) a = (a >= 0.f) ? a : 0.01f*a;
      size_t idx = (((size_t)b*64 + co)*Hn + y)*Wn + x;
      if (res) a += res[idx];
      out[idx] = a;
    }
  }
}

// ---------- depthwise 3x3, pad 1 ----------
__global__ void k_dw3x3(const float* __restrict__ in, const float* __restrict__ w,
                        const float* __restrict__ bias, float* __restrict__ out, int C){
  int bc = blockIdx.x; int y = blockIdx.y; int x = threadIdx.x;
  int c = bc % C;
  const float* ip = in + (size_t)bc*HWn;
  const float* wp = w + c*9;
  float acc = bias ? bias[c] : 0.f;
  #pragma unroll
  for (int ky=0; ky<3; ky++){
    int yy = y + ky - 1; if (yy < 0 || yy >= Hn) continue;
    #pragma unroll
    for (int kx=0; kx<3; kx++){
      int xx = x + kx - 1; if (xx < 0 || xx >= Wn) continue;
      acc = fmaf(ip[yy*Wn+xx], wp[ky*3+kx], acc);
    }
  }
  out[(size_t)bc*HWn + y*Wn + x] = acc;
}

// ---------- pointwise 1x1, register-tiled ----------
template<int CT>
__global__ void k_pwt(const float* __restrict__ in, const float* __restrict__ wg,
                      const float* __restrict__ bias, const float* __restrict__ bng,
                      const float* __restrict__ bnb, float* __restrict__ out,
                      int Cin, int Cout, int npix, int inb, int outb, int post, float slope){
  extern __shared__ float wsm[];
  int nt = (Cout + CT - 1)/CT;
  int b = blockIdx.x / nt, t = blockIdx.x - b*nt;
  int co0 = t*CT;
  for (int i = threadIdx.x; i < CT*Cin; i += 256){
    int co = i / Cin;
    wsm[i] = (co0 + co < Cout) ? wg[(size_t)(co0+co)*Cin + (i - co*Cin)] : 0.f;
  }
  __syncthreads();
  int p = blockIdx.y*256 + threadIdx.x;
  if (p >= npix) return;
  const float* ip = in + (size_t)b*inb + p;
  float acc[CT];
  #pragma unroll
  for (int j=0; j<CT; j++) acc[j] = 0.f;
  for (int ci=0; ci<Cin; ci++){
    float v = ip[(size_t)ci*npix];
    #pragma unroll
    for (int j=0; j<CT; j++) acc[j] = fmaf(v, wsm[j*Cin+ci], acc[j]);
  }
  #pragma unroll
  for (int j=0; j<CT; j++){
    int co = co0 + j;
    if (co < Cout){
      float a = acc[j] + (bias ? bias[co] : 0.f);
      if (bng) a = a*(bng[co]*BN_SCALE) + bnb[co];
      if (post == 1) a = fminf(fmaxf(a, -1.f), 1.f);
      else if (post == 2) a = a*fminf(fmaxf(a+3.f, 0.f), 6.f)*(1.f/6.f);
      else if (post == 3) a = (a >= 0.f) ? a : a*slope;
      out[(size_t)b*outb + (size_t)co*npix + p] = a;
    }
  }
}

// ---------- deformable depthwise 3x3 ----------
__global__ void k_deform(const float* __restrict__ x, const float* __restrict__ off,
                         const float* __restrict__ w, float* __restrict__ out, int C){
  int bc = blockIdx.x; int b = bc / C; int c = bc - b*C;
  int y = blockIdx.y; int x0 = threadIdx.x;
  const float* xp = x + (size_t)bc*HWn;
  const float* op = off + (size_t)b*18*HWn + y*Wn + x0;
  const float* wp = w + c*9;
  float acc = 0.f;
  #pragma unroll
  for (int k=0; k<9; k++){
    int ky = k/3 - 1, kx = k - (k/3)*3 - 1;
    float oy = op[(size_t)(2*k)*HWn];
    float ox = op[(size_t)(2*k+1)*HWn];
    float py = (float)y + (float)ky + oy;
    float px = (float)x0 + (float)kx + ox;
    float fy = floorf(py), fx = floorf(px);
    float wy = py - fy, wx = px - fx;
    int y0 = (int)fy, xx0 = (int)fx;
    float val = 0.f;
    #pragma unroll
    for (int dy=0; dy<2; dy++){
      int iy = y0 + dy; if (iy < 0 || iy >= Hn) continue;
      float wyv = dy ? wy : (1.f - wy);
      #pragma unroll
      for (int dx=0; dx<2; dx++){
        int ix = xx0 + dx; if (ix < 0 || ix >= Wn) continue;
        float wxv = dx ? wx : (1.f - wx);
        val = fmaf(xp[iy*Wn+ix], wyv*wxv, val);
      }
    }
    acc = fmaf(val, wp[k], acc);
  }
  out[(size_t)bc*HWn + y*Wn + x0] = acc;
}

// ---------- small direct conv (final 6->3) ----------
__global__ void k_conv3x3s(const float* __restrict__ in, const float* __restrict__ wgt,
                           const float* __restrict__ bias, const float* __restrict__ res,
                           float* __restrict__ out, int Cin, int Cout){
  int g = blockIdx.x;
  int b = g / Cout; int o0 = g - b*Cout;
  int y = blockIdx.y, x = threadIdx.x;
  float acc = bias ? bias[o0] : 0.f;
  for (int ci=0; ci<Cin; ci++){
    const float* iip = in + ((size_t)b*Cin + ci)*HWn;
    const float* wp = wgt + ((size_t)o0*Cin + ci)*9;
    #pragma unroll
    for (int ky=0; ky<3; ky++){
      int yy = y + ky - 1; if (yy < 0 || yy >= Hn) continue;
      #pragma unroll
      for (int kx=0; kx<3; kx++){
        int xx = x + kx - 1; if (xx < 0 || xx >= Wn) continue;
        acc = fmaf(iip[yy*Wn+xx], wp[ky*3+kx], acc);
      }
    }
  }
  size_t idx = ((size_t)b*Cout + o0)*HWn + y*Wn + x;
  if (res) acc += res[idx];
  out[idx] = acc;
}

// ---------- fused cross-attention: one WG per (b,h) ----------
// scores = q.k/sqrt(8) over w; softmax over d; o = p.v
__global__ __launch_bounds__(256) void k_attn(
    const float* __restrict__ q, const float* __restrict__ k,
    const float* __restrict__ v, float* __restrict__ o){
  __shared__ float qs[64][129];
  __shared__ float ks[64][129];
  __shared__ float vs[64][129];
  __shared__ float ps[64][66];
  int bh = blockIdx.x; int b = bh >> 7, h = bh & 127;
  size_t base = ((size_t)b*64*128 + h)*128;      // + c*HWn + w
  int tid = threadIdx.x;
  for (int e = tid; e < 8192; e += 256){
    int c = e >> 7, w = e & 127;
    size_t g = base + (size_t)c*HWn + w;
    qs[c][w] = q[g]; ks[c][w] = k[g]; vs[c][w] = v[g];
  }
  __syncthreads();
  // scores: 4x4 register tile
  {
    int c0 = (tid >> 4) << 2, d0 = (tid & 15) << 2;
    float acc[4][4];
    #pragma unroll
    for (int a=0; a<4; a++)
      #pragma unroll
      for (int bb=0; bb<4; bb++) acc[a][bb] = 0.f;
    for (int i=0; i<128; i++){
      float qv[4], kv[4];
      #pragma unroll
      for (int a=0; a<4; a++){ qv[a] = qs[c0+a][i]; kv[a] = ks[d0+a][i]; }
      #pragma unroll
      for (int a=0; a<4; a++)
        #pragma unroll
        for (int bb=0; bb<4; bb++) acc[a][bb] = fmaf(qv[a], kv[bb], acc[a][bb]);
    }
    #pragma unroll
    for (int a=0; a<4; a++)
      #pragma unroll
      for (int bb=0; bb<4; bb++)
        ps[c0+a][d0+bb] = acc[a][bb] * 0.35355339059327373f;
  }
  __syncthreads();
  // softmax over d (64 lanes per row)
  {
    int wv = tid >> 6, lane = tid & 63;
    for (int it=0; it<16; it++){
      int row = wv*16 + it;
      float vv = ps[row][lane];
      float m = vv;
      #pragma unroll
      for (int off=32; off; off>>=1) m = fmaxf(m, __shfl_xor(m, off));
      float e = expf(vv - m);
      float s = e;
      #pragma unroll
      for (int off=32; off; off>>=1) s += __shfl_xor(s, off);
      ps[row][lane] = e / s;
    }
  }
  __syncthreads();
  // PV: 4x8 register tile
  {
    int c0 = (tid >> 4) << 2, w0 = (tid & 15) << 3;
    float acc[4][8];
    #pragma unroll
    for (int a=0; a<4; a++)
      #pragma unroll
      for (int j=0; j<8; j++) acc[a][j] = 0.f;
    for (int d=0; d<64; d++){
      float pv[4], vv[8];
      #pragma unroll
      for (int a=0; a<4; a++) pv[a] = ps[c0+a][d];
      #pragma unroll
      for (int j=0; j<8; j++) vv[j] = vs[d][w0+j];
      #pragma unroll
      for (int a=0; a<4; a++)
        #pragma unroll
        for (int j=0; j<8; j++) acc[a][j] = fmaf(pv[a], vv[j], acc[a][j]);
    }
    #pragma unroll
    for (int a=0; a<4; a++)
      #pragma unroll
      for (int j=0; j<8; j++)
        o[base + (size_t)(c0+a)*HWn + w0 + j] = acc[a][j];
  }
}

// ---------- FFT via DFT ----------
__global__ void k_rowfft(const float* __restrict__ x, float* __restrict__ re, float* __restrict__ im){
  __shared__ float xs[128], ct[128], st[128];
  int row = blockIdx.x; int t = threadIdx.x;
  xs[t] = x[(size_t)row*128 + t];
  ct[t] = cosf((float)t * TWOPI_N);
  st[t] = sinf((float)t * TWOPI_N);
  __syncthreads();
  if (t < 65){
    float ar = 0.f, ai = 0.f;
    for (int n=0; n<128; n++){
      int tw = (t*n) & 127;
      ar = fmaf(xs[n], ct[tw], ar);
      ai = fmaf(-xs[n], st[tw], ai);
    }
    re[(size_t)row*65 + t] = ar;
    im[(size_t)row*65 + t] = ai;
  }
}
__global__ void k_colfft(const float* __restrict__ re, const float* __restrict__ im,
                         float* __restrict__ cr, float* __restrict__ ci){
  __shared__ float ct[128], st[128];
  int img = blockIdx.x; int kk = blockIdx.y; int w = threadIdx.x;
  ct[w] = cosf((float)w * TWOPI_N);
  st[w] = sinf((float)w * TWOPI_N);
  __syncthreads();
  if (w < 65){
    const float* rp = re + (size_t)img*HWFn + w;
    const float* ip = im + (size_t)img*HWFn + w;
    float ar = 0.f, ai = 0.f;
    for (int h=0; h<128; h++){
      int tw = (kk*h) & 127;
      float c = ct[tw], s = st[tw];
      float R = rp[h*65], I = ip[h*65];
      ar = fmaf(R, c, fmaf(I, s, ar));
      ai = fmaf(I, c, fmaf(-R, s, ai));
    }
    size_t o = (size_t)img*HWFn + kk*65 + w;
    cr[o] = ar; ci[o] = ai;
  }
}
__global__ void k_magpha(const float* __restrict__ cr, const float* __restrict__ ci,
                         float* __restrict__ dst, int mode, int n){
  int i = blockIdx.x*256 + threadIdx.x;
  if (i >= n) return;
  int img = i / HWFn; int p = i - img*HWFn;
  int b = img >> 6, c = img & 63;
  float R = cr[i], I = ci[i];
  float v = mode ? atan2f(I, R) : sqrtf(R*R + I*I);
  dst[((size_t)b*128 + c)*HWFn + p] = v;
}
__global__ void k_recombine(const float* __restrict__ mo, const float* __restrict__ po,
                            float* __restrict__ R, float* __restrict__ I, int n){
  int i = blockIdx.x*256 + threadIdx.x;
  if (i < n){ float m = mo[i], p = po[i]; R[i] = m*cosf(p); I[i] = m*sinf(p); }
}
__global__ void k_hinv(const float* __restrict__ R, const float* __restrict__ I,
                       float* __restrict__ re2, float* __restrict__ im2){
  __shared__ float ct[128], st[128];
  int img = blockIdx.x; int hh = blockIdx.y; int w = threadIdx.x;
  ct[w] = cosf((float)w * TWOPI_N);
  st[w] = sinf((float)w * TWOPI_N);
  __syncthreads();
  if (w < 65){
    const float* rp = R + (size_t)img*HWFn + w;
    const float* ip = I + (size_t)img*HWFn + w;
    float ar = 0.f, ai = 0.f;
    for (int k2=0; k2<128; k2++){
      int tw = (k2*hh) & 127;
      float c = ct[tw], s = st[tw];
      float Rv = rp[k2*65], Iv = ip[k2*65];
      ar = fmaf(Rv, c, fmaf(-Iv, s, ar));
      ai = fmaf(Rv, s, fmaf(Iv, c, ai));
    }
    size_t o = ((size_t)img*128 + hh)*65 + w;
    re2[o] = ar * (1.f/128.f);
    im2[o] = ai * (1.f/128.f);
  }
}
__global__ void k_winv_add(const float* __restrict__ re2, const float* __restrict__ im2,
                           const float* __restrict__ hsrc, float* __restrict__ outp){
  __shared__ float rs[65], is[65], ct[128], st[128];
  int row = blockIdx.x; int n = threadIdx.x;
  ct[n] = cosf((float)n * TWOPI_N);
  st[n] = sinf((float)n * TWOPI_N);
  if (n < 65){ rs[n] = re2[(size_t)row*65 + n]; is[n] = im2[(size_t)row*65 + n]; }
  __syncthreads();
  float acc = rs[0] + rs[64]*((n & 1) ? -1.f : 1.f);
  for (int k2=1; k2<64; k2++){
    int tw = (k2*n) & 127;
    acc = fmaf(2.f*rs[k2], ct[tw], fmaf(-2.f*is[k2], st[tw], acc));
  }
  acc *= (1.f/128.f);
  outp[(size_t)row*128 + n] = acc + hsrc[(size_t)row*128 + n];
}

} // namespace

extern "C" void kernel_launch(void* const* d_in, const int* in_sizes, int n_in,
                              void* d_out, int out_size, void* d_ws, size_t ws_size,
                              hipStream_t stream){
  const float *xf   =(const float*)d_in[0],  *chodw=(const float*)d_in[1],
              *chopw=(const float*)d_in[2],  *chdcn=(const float*)d_in[3],
              *chpw =(const float*)d_in[4],  *ctodw=(const float*)d_in[5],
              *ctopw=(const float*)d_in[6],  *ctdcn=(const float*)d_in[7],
              *ctpw =(const float*)d_in[8],  *dbw  =(const float*)d_in[9],
              *dbb  =(const float*)d_in[10], *cadw =(const float*)d_in[11],
              *cadb =(const float*)d_in[12], *capw =(const float*)d_in[13],
              *capb =(const float*)d_in[14], *hhw  =(const float*)d_in[15],
              *hhb  =(const float*)d_in[16], *fd1w =(const float*)d_in[17],
              *fd2w =(const float*)d_in[18], *fd1g =(const float*)d_in[19],
              *fd1bt=(const float*)d_in[20], *fd2g =(const float*)d_in[21],
              *fd2bt=(const float*)d_in[22], *fcw  =(const float*)d_in[23],
              *cw   =(const float*)d_in[24], *cb   =(const float*)d_in[25];

  constexpr size_t M = 1048576;            // one batch x 64ch x HW (floats)
  constexpr size_t CF2 = 2ull*64*HWFn;     // 1,064,960
  float* ws = (float*)d_ws;
  float* h     = ws;                       // 12*M
  float* fftHL = ws + 12*M;                // 4*M
  float* cat6  = ws + 16*M;                // 1,179,648
  unsigned short* wpkDB = (unsigned short*)(cat6 + 1179648);
  unsigned short* wpkHH = wpkDB + 552960;
  float* P = cat6 + 1179648 + 313344;      // pool

  const int NB = (ws_size >= 266018816ull) ? 4 : 1;
  const size_t S = (size_t)NB*M;
  float* kb  = P;        float* vb  = P + S;   float* qb  = P + 2*S;
  float* qs  = P + 3*S;  float* aA  = P + 4*S; float* aB  = P + 5*S;
  float* aC  = P + 6*S;  float* hh1 = P + 7*S; float* sA  = P + 8*S;
  float* sB  = P + 9*S;  float* dbuf= P + 10*S;
  float* X   = P + 11*S;
  // phase-1 aliases
  float* dwb3 = P; float* offb12 = P + 589824; float* yb3 = P + 4128768;

  float* out = (float*)d_out;
  float* out0 = out;
  float* out1 = out + 589824;
  float* out2 = out + 589824 + 6389760;

  auto PW = [&](const float* in, const float* wg, const float* bi, const float* g, const float* bt,
                float* o, int B, int Ci, int Co, int npix, int inb, int outb, int post, float slope){
    int py = (npix + 255)/256;
    if (Co > 32){
      k_pwt<32><<<dim3(B*2, py), 256, 32*Ci*4, stream>>>(in, wg, bi, g, bt, o, Ci, Co, npix, inb, outb, post, slope);
    } else if (Co > 18){
      k_pwt<32><<<dim3(B, py), 256, 32*Ci*4, stream>>>(in, wg, bi, g, bt, o, Ci, Co, npix, inb, outb, post, slope);
    } else if (Co > 3){
      k_pwt<18><<<dim3(B, py), 256, 18*Ci*4, stream>>>(in, wg, bi, g, bt, o, Ci, Co, npix, inb, outb, post, slope);
    } else {
      k_pwt<3><<<dim3(B, py), 256, 3*Ci*4, stream>>>(in, wg, bi, g, bt, o, Ci, Co, npix, inb, outb, post, slope);
    }
  };
  auto MCONV = [&](const float* in, const float* in2, const unsigned short* wp, const float* bi,
                   const float* res, float* o, int B, int nblk, int dl, int lk){
    k_mconv<<<B*128, 256, 0, stream>>>(in, in2, wp, bi, res, o, nblk, dl, lk);
  };
  auto DILm = [&](const float* in, int set, const float* bset, int B){
    const unsigned short* w5 = wpkDB + (size_t)set*5*36864;
    MCONV(in, nullptr, w5,          bset,      nullptr, sA,   B, 1, 1, 1);
    MCONV(sA, nullptr, w5+36864,    bset+64,   nullptr, sB,   B, 1, 2, 1);
    MCONV(sB, nullptr, w5+2*36864,  bset+128,  nullptr, sA,   B, 1, 3, 1);
    MCONV(sA, nullptr, w5+3*36864,  bset+192,  nullptr, sB,   B, 1, 2, 1);
    MCONV(sB, nullptr, w5+4*36864,  bset+256,  in,      dbuf, B, 1, 1, 0);
  };
  auto DCONVm = [&](const float* in, int idx, float* o, int B){
    k_dw3x3<<<dim3(B*64, Hn), 128, 0, stream>>>(in, cadw + idx*576, cadb + idx*64, qs, 64);
    PW(qs, capw + (size_t)idx*4096, capb + idx*64, nullptr, nullptr, o, B, 64, 64, HWn, 64*HWn, 64*HWn, 0, 0.f);
  };
  auto ATTNm = [&](const float* qsrc, int qidx, float* o, int B){
    DCONVm(qsrc, qidx, qb, B);
    k_attn<<<B*128, 256, 0, stream>>>(qb, kb, vb, o);
  };
  auto PEMBEDm = [&](const float* in, float* outSlice, int B){
    k_dw3x3<<<dim3(B*64, Hn), 128, 0, stream>>>(in, ctodw, nullptr, qs, 64);
    PW(qs, ctopw, nullptr, nullptr, nullptr, X, B, 64, 18, HWn, 64*HWn, 18*HWn, 1, 0.f);
    k_deform<<<dim3(B*64, Hn), 128, 0, stream>>>(in, X, ctdcn, qs, 64);
    PW(qs, ctpw, nullptr, nullptr, nullptr, outSlice, B, 64, 3, HWn, 64*HWn, 6*HWn, 2, 0.f);
  };

  // ===== Pack conv weights =====
  for (int c=0; c<15; c++)
    k_pack<<<144, 256, 0, stream>>>(dbw + (size_t)c*36864, wpkDB + (size_t)c*36864, 64, 36864);
  k_pack<<<288, 256, 0, stream>>>(hhw, wpkHH, 128, 73728);

  // ===== Phase 1: patch_embed(ch) -> h =====
  k_dw3x3<<<dim3(36, Hn), 128, 0, stream>>>(xf, chodw, nullptr, dwb3, 3);
  PW(dwb3, chopw, nullptr, nullptr, nullptr, offb12, 12, 3, 18, HWn, 3*HWn, 18*HWn, 1, 0.f);
  k_deform<<<dim3(36, Hn), 128, 0, stream>>>(xf, offb12, chdcn, yb3, 3);
  PW(yb3, chpw, nullptr, nullptr, nullptr, h, 12, 3, 64, HWn, 3*HWn, 64*HWn, 2, 0.f);

  // ===== Phase 2: fft_block =====
  if (NB == 4){
    // single pass over all 12 batches (pool = 48M floats >= 4*NF)
    constexpr size_t NF = 12ull*64*HWFn;   // 6,389,760
    constexpr size_t CF = 4ull*64*HWFn;    // 2,129,920
    float* rR = P;           float* rI = P + NF;
    float* cR = P + 2*NF;    float* cI = P + 3*NF;
    float* mB = P;                          // 12x128x8320 = 2*NF (rR/rI dead after colfft)
    k_rowfft<<<98304, 128, 0, stream>>>(h, rR, rI);
    k_colfft<<<dim3(768, 128), 128, 0, stream>>>(rR, rI, cR, cI);
    k_magpha<<<(int)((NF+255)/256), 256, 0, stream>>>(cR, cI, mB, 0, (int)NF);
    PW(mB, fd1w, nullptr, fd1g, fd1bt, mB + 64*HWFn, 12, 64, 32, HWFn, 128*HWFn, 128*HWFn, 3, 0.1f);
    PW(mB, fd2w, nullptr, fd2g, fd2bt, mB + 96*HWFn, 12, 96, 32, HWFn, 128*HWFn, 128*HWFn, 3, 0.1f);
    PW(mB, fcw,  nullptr, nullptr, nullptr, out1,    12, 128, 64, HWFn, 128*HWFn, 64*HWFn, 0, 0.f);
    k_magpha<<<(int)((NF+255)/256), 256, 0, stream>>>(cR, cI, mB, 1, (int)NF);
    PW(mB, fd1w+2048, nullptr, fd1g+32, fd1bt+32, mB + 64*HWFn, 12, 64, 32, HWFn, 128*HWFn, 128*HWFn, 3, 0.1f);
    PW(mB, fd2w+3072, nullptr, fd2g+32, fd2bt+32, mB + 96*HWFn, 12, 96, 32, HWFn, 128*HWFn, 128*HWFn, 3, 0.1f);
    PW(mB, fcw+8192,  nullptr, nullptr, nullptr,  out2, 12, 128, 64, HWFn, 128*HWFn, 64*HWFn, 0, 0.f);
    // irfft2 for batches 0..3 only (fft_LH/fft_HH are slices of h, not fft_out)
    float* R4 = cR;  float* I4 = cR + CF;   // cR/cI dead after pha magpha
    float* re2 = P;  float* im2 = P + CF;   // mB dead after branch PWs
    k_recombine<<<(int)((CF+255)/256), 256, 0, stream>>>(out1, out2, R4, I4, (int)CF);
    k_hinv<<<dim3(256, 128), 128, 0, stream>>>(R4, I4, re2, im2);
    k_winv_add<<<32768, 128, 0, stream>>>(re2, im2, h, fftHL);
  } else {
    float* rowRe = P;            float* rowIm = P + CF2;
    float* colRe = P + 2*CF2;    float* colIm = P + 3*CF2;
    float* magBuf = P;
    float* R4  = colRe;          float* I4  = colIm;
    float* re2 = P;              float* im2 = P + CF2;
    for (int c=0; c<6; c++){
      const float* hsrc = h + (size_t)c*2*M;
      float* o1 = out1 + (size_t)c*CF2;
      float* o2 = out2 + (size_t)c*CF2;
      k_rowfft<<<16384, 128, 0, stream>>>(hsrc, rowRe, rowIm);
      k_colfft<<<dim3(128, 128), 128, 0, stream>>>(rowRe, rowIm, colRe, colIm);
      k_magpha<<<4160, 256, 0, stream>>>(colRe, colIm, magBuf, 0, (int)CF2);
      PW(magBuf, fd1w, nullptr, fd1g, fd1bt, magBuf + 64*HWFn, 2, 64, 32, HWFn, 128*HWFn, 128*HWFn, 3, 0.1f);
      PW(magBuf, fd2w, nullptr, fd2g, fd2bt, magBuf + 96*HWFn, 2, 96, 32, HWFn, 128*HWFn, 128*HWFn, 3, 0.1f);
      PW(magBuf, fcw,  nullptr, nullptr, nullptr, o1,          2, 128, 64, HWFn, 128*HWFn, 64*HWFn, 0, 0.f);
      k_magpha<<<4160, 256, 0, stream>>>(colRe, colIm, magBuf, 1, (int)CF2);
      PW(magBuf, fd1w+2048, nullptr, fd1g+32, fd1bt+32, magBuf + 64*HWFn, 2, 64, 32, HWFn, 128*HWFn, 128*HWFn, 3, 0.1f);
      PW(magBuf, fd2w+3072, nullptr, fd2g+32, fd2bt+32, magBuf + 96*HWFn, 2, 96, 32, HWFn, 128*HWFn, 128*HWFn, 3, 0.1f);
      PW(magBuf, fcw+8192,  nullptr, nullptr, nullptr,  o2,    2, 128, 64, HWFn, 128*HWFn, 64*HWFn, 0, 0.f);
      if (c < 2){
        k_recombine<<<4160, 256, 0, stream>>>(o1, o2, R4, I4, (int)CF2);
        k_hinv<<<dim3(128, 128), 128, 0, stream>>>(R4, I4, re2, im2);
        k_winv_add<<<16384, 128, 0, stream>>>(re2, im2, hsrc, fftHL + (size_t)c*2*M);
      }
    }
  }

  // ===== Phases 3-5 in groups of NB batches =====
  for (int g0=0; g0<4; g0+=NB){
    const float* hHL = h + (size_t)g0*M;
    const float* hLH = h + (size_t)(4+g0)*M;
    const float* hHH = h + (size_t)(8+g0)*M;
    const float* fHL = fftHL + (size_t)g0*M;
    DCONVm(hHH, 1, kb, NB);
    DCONVm(hHH, 2, vb, NB);
    ATTNm(hLH, 0, aA, NB);                       // x_HH_LH (== f_HH_LH)
    DCONVm(hHH, 4, kb, NB);
    DCONVm(hHH, 5, vb, NB);
    ATTNm(hHL, 3, aB, NB);                       // x_HH_HL
    ATTNm(fHL, 3, aC, NB);                       // f_HH_HL
    // x_HH2 path
    MCONV(aA, aB, wpkHH, hhb, nullptr, hh1, NB, 2, 1, 0);
    DILm(hh1, 2, dbb + 2*320, NB);
    PEMBEDm(dbuf, cat6 + (size_t)((8+g0)*6)*HWn, NB);
    // f_HH2 path
    MCONV(aA, aC, wpkHH, hhb, nullptr, hh1, NB, 2, 1, 0);
    DILm(hh1, 2, dbb + 2*320, NB);
    PEMBEDm(dbuf, cat6 + (size_t)((8+g0)*6+3)*HWn, NB);
    // x_HL2 / x_LH2
    DILm(hHL, 1, dbb + 320, NB);
    PEMBEDm(dbuf, cat6 + (size_t)(g0*6)*HWn, NB);
    DILm(hLH, 0, dbb, NB);
    PEMBEDm(dbuf, cat6 + (size_t)((4+g0)*6)*HWn, NB);
    // fft_HL / fft_LH passthroughs
    PEMBEDm(fHL, cat6 + (size_t)(g0*6+3)*HWn, NB);
    PEMBEDm(hLH, cat6 + (size_t)((4+g0)*6+3)*HWn, NB);
  }

  // ===== Final conv + residual -> out0 =====
  k_conv3x3s<<<dim3(36, Hn), 128, 0, stream>>>(cat6, cw, cb, xf, out0, 6, 3);
}

// Round 8
// 3996.228 us; speedup vs baseline: 3.0132x; 1.1439x over previous
//
#include <hip/hip_runtime.h>

namespace {

constexpr int Hn = 128, Wn = 128, HWn = 16384, HWFn = 8320;
constexpr float TWOPI_N = 0.049087385212340526f;   // 2*pi/128
constexpr float BN_SCALE = 0.99999500003749968f;   // 1/sqrt(1+1e-5)

typedef __attribute__((ext_vector_type(8))) short short8;
typedef __attribute__((ext_vector_type(4))) float float4v;

__device__ __forceinline__ short f2bf(float v){
  unsigned u = __float_as_uint(v);
  u += 0x7FFF + ((u >> 16) & 1);          // RNE
  return (short)(u >> 16);
}

// ---------- weight pack to MFMA A-frag order (bf16) ----------
__global__ void k_pack(const float* __restrict__ w, unsigned short* __restrict__ o, int Cin, int n){
  int i = blockIdx.x*256 + threadIdx.x;
  if (i >= n) return;
  int j = i & 7, lane = (i>>3)&63, mt = (i>>9)&3, p = i>>11;
  int blk = p/18, r = p - blk*18, tap = r>>1, ks = r&1;
  int co = mt*16 + (lane & 15);
  int ci = blk*64 + ks*32 + ((lane>>4)<<3) + j;
  o[i] = (unsigned short)f2bf(w[((size_t)co*Cin + ci)*9 + tap]);
}

// ---------- MFMA 3x3 conv: Cout=64, one output row per WG ----------
constexpr int XST = 72;
__global__ __launch_bounds__(256) void k_mconv(
    const float* __restrict__ in, const float* __restrict__ in2,
    const unsigned short* __restrict__ wpk, const float* __restrict__ bias,
    const float* __restrict__ res, float* __restrict__ out,
    int nblk, int dl, int leaky){
  __shared__ short lds[3*134*XST];
  int b = blockIdx.x >> 7, y = blockIdx.x & 127;
  int tid = threadIdx.x;
  int wv = tid >> 6, lane = tid & 63;
  int nq = lane >> 4, nr = lane & 15;
  float4v acc[4][2];
  #pragma unroll
  for (int mt=0; mt<4; mt++)
    #pragma unroll
    for (int nt=0; nt<2; nt++) acc[mt][nt] = (float4v){0.f,0.f,0.f,0.f};

  for (int blk=0; blk<nblk; blk++){
    const float* src = blk ? in2 : in;
    __syncthreads();
    for (int e = tid; e < 3*64*134; e += 256){
      int dy = e / (64*134); int r = e - dy*64*134;
      int ci = r / 134;      int x = r - ci*134;
      int yy = y + (dy-1)*dl;
      int xx = x - 3;
      float v = 0.f;
      if (yy >= 0 && yy < Hn && xx >= 0 && xx < Wn)
        v = src[(((size_t)b*64 + ci)*Hn + yy)*Wn + xx];
      lds[(dy*134 + x)*XST + ci] = f2bf(v);
    }
    __syncthreads();
    const unsigned short* wb = wpk + (size_t)blk*36864;
    for (int tap=0; tap<9; tap++){
      int dy = tap/3, dx = tap - (tap/3)*3;
      #pragma unroll
      for (int ks=0; ks<2; ks++){
        short8 a[4];
        #pragma unroll
        for (int mt=0; mt<4; mt++)
          a[mt] = *(const short8*)(wb + (((size_t)(tap*2+ks)*4+mt)<<9) + ((size_t)lane<<3));
        #pragma unroll
        for (int nt=0; nt<2; nt++){
          int x = wv*32 + nt*16 + nr + (dx-1)*dl + 3;
          short8 bf = *(const short8*)&lds[(dy*134 + x)*XST + ks*32 + nq*8];
          #pragma unroll
          for (int mt=0; mt<4; mt++)
            acc[mt][nt] = __builtin_amdgcn_mfma_f32_16x16x32_bf16(a[mt], bf, acc[mt][nt], 0, 0, 0);
        }
      }
    }
  }
  #pragma unroll
  for (int mt=0; mt<4; mt++)
  #pragma unroll
  for (int nt=0; nt<2; nt++){
    int x = wv*32 + nt*16 + nr;
    #pragma unroll
    for (int r2=0; r2<4; r2++){
      int co = mt*16 + nq*4 + r2;
      float a = acc[mt][nt][r2] + (bias ? bias[co] : 0.f);
      if (leaky) a = (a >= 0.f) ? a : 0.01f*a;
      size_t idx = (((size_t)b*64 + co)*Hn + y)*Wn + x;
      if (res) a += res[idx];
      out[idx] = a;
    }
  }
}

// ---------- depthwise 3x3, pad 1 ----------
__global__ void k_dw3x3(const float* __restrict__ in, const float* __restrict__ w,
                        const float* __restrict__ bias, float* __restrict__ out, int C){
  int bc = blockIdx.x; int y = blockIdx.y; int x = threadIdx.x;
  int c = bc % C;
  const float* ip = in + (size_t)bc*HWn;
  const float* wp = w + c*9;
  float acc = bias ? bias[c] : 0.f;
  #pragma unroll
  for (int ky=0; ky<3; ky++){
    int yy = y + ky - 1; if (yy < 0 || yy >= Hn) continue;
    #pragma unroll
    for (int kx=0; kx<3; kx++){
      int xx = x + kx - 1; if (xx < 0 || xx >= Wn) continue;
      acc = fmaf(ip[yy*Wn+xx], wp[ky*3+kx], acc);
    }
  }
  out[(size_t)bc*HWn + y*Wn + x] = acc;
}

// ---------- pointwise 1x1, register-tiled ----------
template<int CT>
__global__ void k_pwt(const float* __restrict__ in, const float* __restrict__ wg,
                      const float* __restrict__ bias, const float* __restrict__ bng,
                      const float* __restrict__ bnb, float* __restrict__ out,
                      int Cin, int Cout, int npix, int inb, int outb, int post, float slope){
  extern __shared__ float wsm[];
  int nt = (Cout + CT - 1)/CT;
  int b = blockIdx.x / nt, t = blockIdx.x - b*nt;
  int co0 = t*CT;
  for (int i = threadIdx.x; i < CT*Cin; i += 256){
    int co = i / Cin;
    wsm[i] = (co0 + co < Cout) ? wg[(size_t)(co0+co)*Cin + (i - co*Cin)] : 0.f;
  }
  __syncthreads();
  int p = blockIdx.y*256 + threadIdx.x;
  if (p >= npix) return;
  const float* ip = in + (size_t)b*inb + p;
  float acc[CT];
  #pragma unroll
  for (int j=0; j<CT; j++) acc[j] = 0.f;
  for (int ci=0; ci<Cin; ci++){
    float v = ip[(size_t)ci*npix];
    #pragma unroll
    for (int j=0; j<CT; j++) acc[j] = fmaf(v, wsm[j*Cin+ci], acc[j]);
  }
  #pragma unroll
  for (int j=0; j<CT; j++){
    int co = co0 + j;
    if (co < Cout){
      float a = acc[j] + (bias ? bias[co] : 0.f);
      if (bng) a = a*(bng[co]*BN_SCALE) + bnb[co];
      if (post == 1) a = fminf(fmaxf(a, -1.f), 1.f);
      else if (post == 2) a = a*fminf(fmaxf(a+3.f, 0.f), 6.f)*(1.f/6.f);
      else if (post == 3) a = (a >= 0.f) ? a : a*slope;
      out[(size_t)b*outb + (size_t)co*npix + p] = a;
    }
  }
}

// ---------- deformable depthwise 3x3 ----------
__global__ void k_deform(const float* __restrict__ x, const float* __restrict__ off,
                         const float* __restrict__ w, float* __restrict__ out, int C){
  int bc = blockIdx.x; int b = bc / C; int c = bc - b*C;
  int y = blockIdx.y; int x0 = threadIdx.x;
  const float* xp = x + (size_t)bc*HWn;
  const float* op = off + (size_t)b*18*HWn + y*Wn + x0;
  const float* wp = w + c*9;
  float acc = 0.f;
  #pragma unroll
  for (int k=0; k<9; k++){
    int ky = k/3 - 1, kx = k - (k/3)*3 - 1;
    float oy = op[(size_t)(2*k)*HWn];
    float ox = op[(size_t)(2*k+1)*HWn];
    float py = (float)y + (float)ky + oy;
    float px = (float)x0 + (float)kx + ox;
    float fy = floorf(py), fx = floorf(px);
    float wy = py - fy, wx = px - fx;
    int y0 = (int)fy, xx0 = (int)fx;
    float val = 0.f;
    #pragma unroll
    for (int dy=0; dy<2; dy++){
      int iy = y0 + dy; if (iy < 0 || iy >= Hn) continue;
      float wyv = dy ? wy : (1.f - wy);
      #pragma unroll
      for (int dx=0; dx<2; dx++){
        int ix = xx0 + dx; if (ix < 0 || ix >= Wn) continue;
        float wxv = dx ? wx : (1.f - wx);
        val = fmaf(xp[iy*Wn+ix], wyv*wxv, val);
      }
    }
    acc = fmaf(val, wp[k], acc);
  }
  out[(size_t)bc*HWn + y*Wn + x0] = acc;
}

// ---------- small direct conv (final 6->3) ----------
__global__ void k_conv3x3s(const float* __restrict__ in, const float* __restrict__ wgt,
                           const float* __restrict__ bias, const float* __restrict__ res,
                           float* __restrict__ out, int Cin, int Cout){
  int g = blockIdx.x;
  int b = g / Cout; int o0 = g - b*Cout;
  int y = blockIdx.y, x = threadIdx.x;
  float acc = bias ? bias[o0] : 0.f;
  for (int ci=0; ci<Cin; ci++){
    const float* iip = in + ((size_t)b*Cin + ci)*HWn;
    const float* wp = wgt + ((size_t)o0*Cin + ci)*9;
    #pragma unroll
    for (int ky=0; ky<3; ky++){
      int yy = y + ky - 1; if (yy < 0 || yy >= Hn) continue;
      #pragma unroll
      for (int kx=0; kx<3; kx++){
        int xx = x + kx - 1; if (xx < 0 || xx >= Wn) continue;
        acc = fmaf(iip[yy*Wn+xx], wp[ky*3+kx], acc);
      }
    }
  }
  size_t idx = ((size_t)b*Cout + o0)*HWn + y*Wn + x;
  if (res) acc += res[idx];
  out[idx] = acc;
}

// ---------- fused cross-attention: one WG per (b,h) ----------
__global__ __launch_bounds__(256) void k_attn(
    const float* __restrict__ q, const float* __restrict__ k,
    const float* __restrict__ v, float* __restrict__ o){
  __shared__ float qs[64][129];
  __shared__ float ks[64][129];
  __shared__ float vs[64][129];
  __shared__ float ps[64][66];
  int bh = blockIdx.x; int b = bh >> 7, h = bh & 127;
  size_t base = ((size_t)b*64*128 + h)*128;
  int tid = threadIdx.x;
  for (int e = tid; e < 8192; e += 256){
    int c = e >> 7, w = e & 127;
    size_t g = base + (size_t)c*HWn + w;
    qs[c][w] = q[g]; ks[c][w] = k[g]; vs[c][w] = v[g];
  }
  __syncthreads();
  {
    int c0 = (tid >> 4) << 2, d0 = (tid & 15) << 2;
    float acc[4][4];
    #pragma unroll
    for (int a=0; a<4; a++)
      #pragma unroll
      for (int bb=0; bb<4; bb++) acc[a][bb] = 0.f;
    for (int i=0; i<128; i++){
      float qv[4], kv[4];
      #pragma unroll
      for (int a=0; a<4; a++){ qv[a] = qs[c0+a][i]; kv[a] = ks[d0+a][i]; }
      #pragma unroll
      for (int a=0; a<4; a++)
        #pragma unroll
        for (int bb=0; bb<4; bb++) acc[a][bb] = fmaf(qv[a], kv[bb], acc[a][bb]);
    }
    #pragma unroll
    for (int a=0; a<4; a++)
      #pragma unroll
      for (int bb=0; bb<4; bb++)
        ps[c0+a][d0+bb] = acc[a][bb] * 0.35355339059327373f;
  }
  __syncthreads();
  {
    int wv = tid >> 6, lane = tid & 63;
    for (int it=0; it<16; it++){
      int row = wv*16 + it;
      float vv = ps[row][lane];
      float m = vv;
      #pragma unroll
      for (int off=32; off; off>>=1) m = fmaxf(m, __shfl_xor(m, off));
      float e = expf(vv - m);
      float s = e;
      #pragma unroll
      for (int off=32; off; off>>=1) s += __shfl_xor(s, off);
      ps[row][lane] = e / s;
    }
  }
  __syncthreads();
  {
    int c0 = (tid >> 4) << 2, w0 = (tid & 15) << 3;
    float acc[4][8];
    #pragma unroll
    for (int a=0; a<4; a++)
      #pragma unroll
      for (int j=0; j<8; j++) acc[a][j] = 0.f;
    for (int d=0; d<64; d++){
      float pv[4], vv[8];
      #pragma unroll
      for (int a=0; a<4; a++) pv[a] = ps[c0+a][d];
      #pragma unroll
      for (int j=0; j<8; j++) vv[j] = vs[d][w0+j];
      #pragma unroll
      for (int a=0; a<4; a++)
        #pragma unroll
        for (int j=0; j<8; j++) acc[a][j] = fmaf(pv[a], vv[j], acc[a][j]);
    }
    #pragma unroll
    for (int a=0; a<4; a++)
      #pragma unroll
      for (int j=0; j<8; j++)
        o[base + (size_t)(c0+a)*HWn + w0 + j] = acc[a][j];
  }
}

// ---------- fused rfft2 + mag/pha: one WG per image plane ----------
// x: [B*64][128][128]; mag/pha: [B][128ch][8320], write ch 0..63
__global__ __launch_bounds__(256) void k_fft2(
    const float* __restrict__ x, float* __restrict__ mag, float* __restrict__ pha){
  __shared__ float xs[16384];       // [r][n]
  __shared__ float spec[16640];     // [r][t] complex interleaved (128*65*2)
  int img = blockIdx.x;
  int tid = threadIdx.x;
  const float* xp = x + (size_t)img*HWn;
  for (int e = tid; e < 4096; e += 256)
    ((float4*)xs)[e] = ((const float4*)xp)[e];
  __syncthreads();
  // row DFT: out (r,t) -> spec[(r*65+t)*2]; lanes share r (broadcast xs), per-lane twiddle recurrence
  for (int i = tid; i < 8320; i += 256){
    int r = i/65, t = i - r*65;
    float sc = cosf((float)t*TWOPI_N), ss = -sinf((float)t*TWOPI_N);
    float zr = 1.f, zi = 0.f, ar = 0.f, ai = 0.f;
    const float4* xr = (const float4*)&xs[r*128];
    for (int n4 = 0; n4 < 32; n4++){
      float4 xv = xr[n4];
      #pragma unroll
      for (int q=0; q<4; q++){
        float xq = (q==0)?xv.x:(q==1)?xv.y:(q==2)?xv.z:xv.w;
        ar = fmaf(xq, zr, ar);
        ai = fmaf(xq, zi, ai);
        float t0 = zr*sc - zi*ss;
        zi = fmaf(zr, ss, zi*sc);
        zr = t0;
      }
    }
    spec[2*i] = ar; spec[2*i+1] = ai;
  }
  __syncthreads();
  // col DFT + mag/pha: out (kk,w); lanes consecutive w (coalesced LDS float2)
  int b = img >> 6, ch = img & 63;
  float* mp = mag + ((size_t)b*128 + ch)*HWFn;
  float* pp = pha + ((size_t)b*128 + ch)*HWFn;
  for (int i = tid; i < 8320; i += 256){
    int kk = i/65, w = i - kk*65;
    float sc = cosf((float)kk*TWOPI_N), ss = -sinf((float)kk*TWOPI_N);
    float zr = 1.f, zi = 0.f, ar = 0.f, ai = 0.f;
    for (int hh=0; hh<128; hh++){
      float2 v = *(const float2*)&spec[(hh*65+w)*2];
      ar = fmaf(v.x, zr, fmaf(-v.y, zi, ar));
      ai = fmaf(v.y, zr, fmaf(v.x, zi, ai));
      float t0 = zr*sc - zi*ss;
      zi = fmaf(zr, ss, zi*sc);
      zr = t0;
    }
    mp[i] = sqrtf(ar*ar + ai*ai);
    pp[i] = atan2f(ai, ar);
  }
}

// ---------- fused irfft2 + residual add: one WG per image plane (256 imgs) ----------
// mo/po: [256 img][8320] (= out1/out2 head); hsrc/outp: [256 img][16384]
__global__ __launch_bounds__(256) void k_ifft2(
    const float* __restrict__ mo, const float* __restrict__ po,
    const float* __restrict__ hsrc, float* __restrict__ outp){
  __shared__ float spec[16640];     // [kk][w] complex
  __shared__ float spec2[16640];    // [hh][w] complex
  int img = blockIdx.x;
  int tid = threadIdx.x;
  const float* mp = mo + (size_t)img*HWFn;
  const float* pp = po + (size_t)img*HWFn;
  for (int i = tid; i < 8320; i += 256){
    float m = mp[i], p = pp[i];
    float s, c; sincosf(p, &s, &c);
    spec[2*i] = m*c; spec[2*i+1] = m*s;
  }
  __syncthreads();
  // column inverse: out (hh,w) = sum_k2 (R+iI)[k2][w] * e^{+i k2 hh d}
  for (int i = tid; i < 8320; i += 256){
    int hh = i/65, w = i - hh*65;
    float sc = cosf((float)hh*TWOPI_N), ss = sinf((float)hh*TWOPI_N);
    float zr = 1.f, zi = 0.f, ar = 0.f, ai = 0.f;
    for (int k2=0; k2<128; k2++){
      float2 v = *(const float2*)&spec[(k2*65+w)*2];
      ar = fmaf(v.x, zr, fmaf(-v.y, zi, ar));
      ai = fmaf(v.x, zi, fmaf(v.y, zr, ai));
      float t0 = zr*sc - zi*ss;
      zi = fmaf(zr, ss, zi*sc);
      zr = t0;
    }
    spec2[2*i] = ar; spec2[2*i+1] = ai;
  }
  __syncthreads();
  // row inverse c2r + add residual: out (r,n); lanes consecutive n, spec2 reads broadcast
  for (int i = tid; i < 16384; i += 256){
    int r = i >> 7, n = i & 127;
    float sc = cosf((float)n*TWOPI_N), ss = sinf((float)n*TWOPI_N);
    float zr = sc, zi = ss;           // k=1 twiddle
    const float* row = &spec2[r*130]; // 65 complex
    float acc = 0.5f*(row[0] + ((n & 1) ? -row[128] : row[128]));
    for (int k=1; k<64; k++){
      float2 v = *(const float2*)&row[2*k];
      acc = fmaf(v.x, zr, fmaf(-v.y, zi, acc));
      float t0 = zr*sc - zi*ss;
      zi = fmaf(zr, ss, zi*sc);
      zr = t0;
    }
    acc *= (1.f/8192.f);
    size_t gi = (size_t)img*HWn + i;
    outp[gi] = acc + hsrc[gi];
  }
}

} // namespace

extern "C" void kernel_launch(void* const* d_in, const int* in_sizes, int n_in,
                              void* d_out, int out_size, void* d_ws, size_t ws_size,
                              hipStream_t stream){
  const float *xf   =(const float*)d_in[0],  *chodw=(const float*)d_in[1],
              *chopw=(const float*)d_in[2],  *chdcn=(const float*)d_in[3],
              *chpw =(const float*)d_in[4],  *ctodw=(const float*)d_in[5],
              *ctopw=(const float*)d_in[6],  *ctdcn=(const float*)d_in[7],
              *ctpw =(const float*)d_in[8],  *dbw  =(const float*)d_in[9],
              *dbb  =(const float*)d_in[10], *cadw =(const float*)d_in[11],
              *cadb =(const float*)d_in[12], *capw =(const float*)d_in[13],
              *capb =(const float*)d_in[14], *hhw  =(const float*)d_in[15],
              *hhb  =(const float*)d_in[16], *fd1w =(const float*)d_in[17],
              *fd2w =(const float*)d_in[18], *fd1g =(const float*)d_in[19],
              *fd1bt=(const float*)d_in[20], *fd2g =(const float*)d_in[21],
              *fd2bt=(const float*)d_in[22], *fcw  =(const float*)d_in[23],
              *cw   =(const float*)d_in[24], *cb   =(const float*)d_in[25];

  constexpr size_t M = 1048576;            // one batch x 64ch x HW (floats)
  float* ws = (float*)d_ws;
  float* h     = ws;                       // 12*M
  float* fftHL = ws + 12*M;                // 4*M
  float* cat6  = ws + 16*M;                // 1,179,648
  unsigned short* wpkDB = (unsigned short*)(cat6 + 1179648);
  unsigned short* wpkHH = wpkDB + 552960;
  float* P = cat6 + 1179648 + 313344;      // pool

  const int NB = (ws_size >= 266018816ull) ? 4 : 1;
  const size_t S = (size_t)NB*M;
  float* kb  = P;        float* vb  = P + S;   float* qb  = P + 2*S;
  float* qs  = P + 3*S;  float* aA  = P + 4*S; float* aB  = P + 5*S;
  float* aC  = P + 6*S;  float* hh1 = P + 7*S; float* sA  = P + 8*S;
  float* sB  = P + 9*S;  float* dbuf= P + 10*S;
  float* X   = P + 11*S;
  // phase-1 aliases
  float* dwb3 = P; float* offb12 = P + 589824; float* yb3 = P + 4128768;

  float* out = (float*)d_out;
  float* out0 = out;
  float* out1 = out + 589824;
  float* out2 = out + 589824 + 6389760;

  auto PW = [&](const float* in, const float* wg, const float* bi, const float* g, const float* bt,
                float* o, int B, int Ci, int Co, int npix, int inb, int outb, int post, float slope){
    int py = (npix + 255)/256;
    if (Co > 32){
      k_pwt<32><<<dim3(B*2, py), 256, 32*Ci*4, stream>>>(in, wg, bi, g, bt, o, Ci, Co, npix, inb, outb, post, slope);
    } else if (Co > 18){
      k_pwt<32><<<dim3(B, py), 256, 32*Ci*4, stream>>>(in, wg, bi, g, bt, o, Ci, Co, npix, inb, outb, post, slope);
    } else if (Co > 3){
      k_pwt<18><<<dim3(B, py), 256, 18*Ci*4, stream>>>(in, wg, bi, g, bt, o, Ci, Co, npix, inb, outb, post, slope);
    } else {
      k_pwt<3><<<dim3(B, py), 256, 3*Ci*4, stream>>>(in, wg, bi, g, bt, o, Ci, Co, npix, inb, outb, post, slope);
    }
  };
  auto MCONV = [&](const float* in, const float* in2, const unsigned short* wp, const float* bi,
                   const float* res, float* o, int B, int nblk, int dl, int lk){
    k_mconv<<<B*128, 256, 0, stream>>>(in, in2, wp, bi, res, o, nblk, dl, lk);
  };
  auto DILm = [&](const float* in, int set, const float* bset, int B){
    const unsigned short* w5 = wpkDB + (size_t)set*5*36864;
    MCONV(in, nullptr, w5,          bset,      nullptr, sA,   B, 1, 1, 1);
    MCONV(sA, nullptr, w5+36864,    bset+64,   nullptr, sB,   B, 1, 2, 1);
    MCONV(sB, nullptr, w5+2*36864,  bset+128,  nullptr, sA,   B, 1, 3, 1);
    MCONV(sA, nullptr, w5+3*36864,  bset+192,  nullptr, sB,   B, 1, 2, 1);
    MCONV(sB, nullptr, w5+4*36864,  bset+256,  in,      dbuf, B, 1, 1, 0);
  };
  auto DCONVm = [&](const float* in, int idx, float* o, int B){
    k_dw3x3<<<dim3(B*64, Hn), 128, 0, stream>>>(in, cadw + idx*576, cadb + idx*64, qs, 64);
    PW(qs, capw + (size_t)idx*4096, capb + idx*64, nullptr, nullptr, o, B, 64, 64, HWn, 64*HWn, 64*HWn, 0, 0.f);
  };
  auto ATTNm = [&](const float* qsrc, int qidx, float* o, int B){
    DCONVm(qsrc, qidx, qb, B);
    k_attn<<<B*128, 256, 0, stream>>>(qb, kb, vb, o);
  };
  auto PEMBEDm = [&](const float* in, float* outSlice, int B){
    k_dw3x3<<<dim3(B*64, Hn), 128, 0, stream>>>(in, ctodw, nullptr, qs, 64);
    PW(qs, ctopw, nullptr, nullptr, nullptr, X, B, 64, 18, HWn, 64*HWn, 18*HWn, 1, 0.f);
    k_deform<<<dim3(B*64, Hn), 128, 0, stream>>>(in, X, ctdcn, qs, 64);
    PW(qs, ctpw, nullptr, nullptr, nullptr, outSlice, B, 64, 3, HWn, 64*HWn, 6*HWn, 2, 0.f);
  };

  // ===== Pack conv weights =====
  for (int c=0; c<15; c++)
    k_pack<<<144, 256, 0, stream>>>(dbw + (size_t)c*36864, wpkDB + (size_t)c*36864, 64, 36864);
  k_pack<<<288, 256, 0, stream>>>(hhw, wpkHH, 128, 73728);

  // ===== Phase 1: patch_embed(ch) -> h =====
  k_dw3x3<<<dim3(36, Hn), 128, 0, stream>>>(xf, chodw, nullptr, dwb3, 3);
  PW(dwb3, chopw, nullptr, nullptr, nullptr, offb12, 12, 3, 18, HWn, 3*HWn, 18*HWn, 1, 0.f);
  k_deform<<<dim3(36, Hn), 128, 0, stream>>>(xf, offb12, chdcn, yb3, 3);
  PW(yb3, chpw, nullptr, nullptr, nullptr, h, 12, 3, 64, HWn, 3*HWn, 64*HWn, 2, 0.f);

  // ===== Phase 2: fft_block (fused LDS-resident 2-D DFT) =====
  if (NB == 4){
    float* mB = P;                 // [12][128][8320]
    float* pB = P + 12779520;
    k_fft2<<<768, 256, 0, stream>>>(h, mB, pB);
    PW(mB, fd1w, nullptr, fd1g, fd1bt, mB + 64*HWFn, 12, 64, 32, HWFn, 128*HWFn, 128*HWFn, 3, 0.1f);
    PW(mB, fd2w, nullptr, fd2g, fd2bt, mB + 96*HWFn, 12, 96, 32, HWFn, 128*HWFn, 128*HWFn, 3, 0.1f);
    PW(mB, fcw,  nullptr, nullptr, nullptr, out1,    12, 128, 64, HWFn, 128*HWFn, 64*HWFn, 0, 0.f);
    PW(pB, fd1w+2048, nullptr, fd1g+32, fd1bt+32, pB + 64*HWFn, 12, 64, 32, HWFn, 128*HWFn, 128*HWFn, 3, 0.1f);
    PW(pB, fd2w+3072, nullptr, fd2g+32, fd2bt+32, pB + 96*HWFn, 12, 96, 32, HWFn, 128*HWFn, 128*HWFn, 3, 0.1f);
    PW(pB, fcw+8192,  nullptr, nullptr, nullptr,  out2, 12, 128, 64, HWFn, 128*HWFn, 64*HWFn, 0, 0.f);
    k_ifft2<<<256, 256, 0, stream>>>(out1, out2, h, fftHL);
  } else {
    // 3 chunks of 4 batches
    float* mB = P;                 // [4][128][8320]
    float* pB = P + 4259840;
    for (int c=0; c<3; c++){
      const float* hsrc = h + (size_t)c*4*M;
      float* o1 = out1 + (size_t)c*2129920;
      float* o2 = out2 + (size_t)c*2129920;
      k_fft2<<<256, 256, 0, stream>>>(hsrc, mB, pB);
      PW(mB, fd1w, nullptr, fd1g, fd1bt, mB + 64*HWFn, 4, 64, 32, HWFn, 128*HWFn, 128*HWFn, 3, 0.1f);
      PW(mB, fd2w, nullptr, fd2g, fd2bt, mB + 96*HWFn, 4, 96, 32, HWFn, 128*HWFn, 128*HWFn, 3, 0.1f);
      PW(mB, fcw,  nullptr, nullptr, nullptr, o1,      4, 128, 64, HWFn, 128*HWFn, 64*HWFn, 0, 0.f);
      PW(pB, fd1w+2048, nullptr, fd1g+32, fd1bt+32, pB + 64*HWFn, 4, 64, 32, HWFn, 128*HWFn, 128*HWFn, 3, 0.1f);
      PW(pB, fd2w+3072, nullptr, fd2g+32, fd2bt+32, pB + 96*HWFn, 4, 96, 32, HWFn, 128*HWFn, 128*HWFn, 3, 0.1f);
      PW(pB, fcw+8192,  nullptr, nullptr, nullptr,  o2, 4, 128, 64, HWFn, 128*HWFn, 64*HWFn, 0, 0.f);
      if (c == 0)
        k_ifft2<<<256, 256, 0, stream>>>(out1, out2, h, fftHL);
    }
  }

  // ===== Phases 3-5 in groups of NB batches =====
  for (int g0=0; g0<4; g0+=NB){
    const float* hHL = h + (size_t)g0*M;
    const float* hLH = h + (size_t)(4+g0)*M;
    const float* hHH = h + (size_t)(8+g0)*M;
    const float* fHL = fftHL + (size_t)g0*M;
    DCONVm(hHH, 1, kb, NB);
    DCONVm(hHH, 2, vb, NB);
    ATTNm(hLH, 0, aA, NB);                       // x_HH_LH (== f_HH_LH)
    DCONVm(hHH, 4, kb, NB);
    DCONVm(hHH, 5, vb, NB);
    ATTNm(hHL, 3, aB, NB);                       // x_HH_HL
    ATTNm(fHL, 3, aC, NB);                       // f_HH_HL
    // x_HH2 path
    MCONV(aA, aB, wpkHH, hhb, nullptr, hh1, NB, 2, 1, 0);
    DILm(hh1, 2, dbb + 2*320, NB);
    PEMBEDm(dbuf, cat6 + (size_t)((8+g0)*6)*HWn, NB);
    // f_HH2 path
    MCONV(aA, aC, wpkHH, hhb, nullptr, hh1, NB, 2, 1, 0);
    DILm(hh1, 2, dbb + 2*320, NB);
    PEMBEDm(dbuf, cat6 + (size_t)((8+g0)*6+3)*HWn, NB);
    // x_HL2 / x_LH2
    DILm(hHL, 1, dbb + 320, NB);
    PEMBEDm(dbuf, cat6 + (size_t)(g0*6)*HWn, NB);
    DILm(hLH, 0, dbb, NB);
    PEMBEDm(dbuf, cat6 + (size_t)((4+g0)*6)*HWn, NB);
    // fft_HL / fft_LH passthroughs
    PEMBEDm(fHL, cat6 + (size_t)(g0*6+3)*HWn, NB);
    PEMBEDm(hLH, cat6 + (size_t)((4+g0)*6+3)*HWn, NB);
  }

  // ===== Final conv + residual -> out0 =====
  k_conv3x3s<<<dim3(36, Hn), 128, 0, stream>>>(cat6, cw, cb, xf, out0, 6, 3);
}